// Round 6
// baseline (99.457 us; speedup 1.0000x reference)
//
#include <hip/hip_runtime.h>
#include <hip/hip_bf16.h>

// SparseGCM: 2-layer causal-window GCN on MI355X — split-bf16, barrier-free
// register-pipelined MFMA GEMM.
// Edges are j->i for j in [i-16,i) per batch, weights normalize to 1.0 ->
// "gather+segment_sum" == 16-wide sliding-window sum. Only outputs i in
// [512,640) matter: layer1 computes i in [496,640).
//
// Precision (R2/R4 lessons): single-bf16 fails — temporally-correlated L1
// errors are amplified x16 by the L2 window sum. Split v = hi + lo (bf16
// pair); compute A_hi*W_hi + A_hi*W_lo + A_lo*W_hi (3 MFMAs) ~= fp32.
// A packed [s_hi|s_lo|win_hi|win_lo] (K=1024); W1=[ws_hi|wn_hi],
// W2=[ws_lo|wn_lo] (K=512). Validated in R5 (absmax 0.0039).
//
// Perf (R5 lesson): LDS 2-phase loop stalls on the per-K-step vmcnt(0) drain
// (MfmaUtil 5%). R6: no LDS, no barriers — per-wave 32x32 tiles, fragments
// loaded straight from global with a fully-unrolled 3-buffer rotation
// (depth-2 prefetch), latency hidden by wave-level TLP.

namespace {

constexpr int BQ    = 64;
constexpr int FEATC = 256;
constexpr int M1 = 144;   // layer-1 rows/batch: i in [496,640)
constexpr int M2 = 128;   // layer-2 rows/batch: i in [512,640)
constexpr int KK = 1024;  // A packed K
constexpr int KW = 512;   // W packed K

using ushort = unsigned short;
using short8 = __attribute__((ext_vector_type(8))) short;   // 8 bf16
using f32x4  = __attribute__((ext_vector_type(4))) float;

__device__ __forceinline__ ushort f2bf(float f) {  // RNE
  union { float f; unsigned u; } v{f};
  unsigned r = v.u + 0x7FFFu + ((v.u >> 16) & 1u);
  return (ushort)(r >> 16);
}
__device__ __forceinline__ float bf2f(ushort h) {
  union { unsigned u; float f; } v{(unsigned)h << 16};
  return v.f;
}
__device__ __forceinline__ void split2(float v, ushort& hi, ushort& lo) {
  hi = f2bf(v);
  lo = f2bf(v - bf2f(hi));
}

// ---------------------------------------------------------------------------
// prep_fused: blocks [0,576) = prep1 (b=blk/9, chunk=blk%9);
//             blocks [576,640) = wprep (transpose+split weights).
// prep1: Acat1[b*144+t][1024]: [f]=s_hi [256+f]=s_lo [512+f]=win_hi [768+f]=win_lo
// wprep: W1x[n][512]=[ws_hi|wn_hi], W2x[n][512]=[ws_lo|wn_lo]
// ---------------------------------------------------------------------------
__global__ __launch_bounds__(256) void prep_fused(
    const float* __restrict__ x, const float* __restrict__ nodes,
    const float* __restrict__ W1s, const float* __restrict__ W1n,
    const float* __restrict__ W2s, const float* __restrict__ W2n,
    ushort* __restrict__ Acat1,
    ushort* __restrict__ W1_1, ushort* __restrict__ W2_1,
    ushort* __restrict__ W1_2, ushort* __restrict__ W2_2) {
  __shared__ float tile[64][65];
  const int blk = blockIdx.x;
  if (blk < 576) {
    // ---- prep1 ----
    const int b = blk / 9, c = blk % 9, f = threadIdx.x;
    const int t0 = c * 16, i0 = 496 + t0;
    const float* nb = nodes + ((size_t)b * 640) * FEATC + f;
    const float* xb = x     + ((size_t)b * 128) * FEATC + f;

    float v[32];
    #pragma unroll
    for (int d = 0; d < 32; ++d) {
      const int i = i0 - 16 + d;
      v[d] = (i < 512) ? nb[(size_t)i * FEATC] : xb[(size_t)(i - 512) * FEATC];
    }
    float win = 0.f;
    #pragma unroll
    for (int d = 0; d < 16; ++d) win += v[d];

    ushort* ao = Acat1 + ((size_t)(b * M1 + t0)) * KK + f;
    #pragma unroll
    for (int tt = 0; tt < 16; ++tt) {
      ushort hi, lo;
      split2(v[16 + tt], hi, lo);
      ao[(size_t)tt * KK]       = hi;
      ao[(size_t)tt * KK + 256] = lo;
      split2(win, hi, lo);
      ao[(size_t)tt * KK + 512] = hi;
      ao[(size_t)tt * KK + 768] = lo;
      win += v[16 + tt] - v[tt];
    }
  } else {
    // ---- wprep ----
    const int w = blk - 576;
    const int z = w >> 4, rem = w & 15;
    const int k0 = (rem >> 2) * 64, n0 = (rem & 3) * 64;
    const float* src = (z == 0) ? W1s : (z == 1) ? W1n : (z == 2) ? W2s : W2n;
    ushort* dstH = (z < 2) ? W1_1 : W1_2;
    ushort* dstL = (z < 2) ? W2_1 : W2_2;
    const int koff = (z & 1) * 256;
    const int c = threadIdx.x & 63, r4 = threadIdx.x >> 6;
    #pragma unroll
    for (int p = 0; p < 16; ++p) {
      const int k = r4 + p * 4;
      tile[k][c] = src[(size_t)(k0 + k) * FEATC + n0 + c];
    }
    __syncthreads();
    #pragma unroll
    for (int p = 0; p < 16; ++p) {
      const int n = r4 + p * 4;
      ushort hi, lo;
      split2(tile[c][n], hi, lo);
      dstH[(size_t)(n0 + n) * KW + koff + k0 + c] = hi;
      dstL[(size_t)(n0 + n) * KW + koff + k0 + c] = lo;
    }
  }
}

// ---------------------------------------------------------------------------
// prep2: fill window segments of Acat2 (self segs written by gemm1 epilogue).
// h1 row j (i=496+j): j<16 in h1head{hi,lo}[b*16+j][f]; j>=16 in Acat2 row
// b*128+(j-16) at [f](hi)/[256+f](lo). Output t: window = h1 rows [t,t+16).
// ---------------------------------------------------------------------------
__global__ __launch_bounds__(256) void prep2_kernel(
    const ushort* __restrict__ h1hhi, const ushort* __restrict__ h1hlo,
    ushort* __restrict__ Acat2) {
  const int b = blockIdx.x, c = blockIdx.y, f = threadIdx.x;
  const int t0 = c * 16;

  float hv[32];
  #pragma unroll
  for (int d = 0; d < 32; ++d) {
    const int j = t0 + d;
    if (j < 16) {
      const size_t o = (size_t)(b * 16 + j) * FEATC + f;
      hv[d] = bf2f(h1hhi[o]) + bf2f(h1hlo[o]);
    } else {
      const size_t o = (size_t)(b * M2 + (j - 16)) * KK + f;
      hv[d] = bf2f(Acat2[o]) + bf2f(Acat2[o + 256]);
    }
  }
  float win = 0.f;
  #pragma unroll
  for (int d = 0; d < 16; ++d) win += hv[d];

  ushort* ao = Acat2 + ((size_t)(b * M2 + t0)) * KK + f;
  #pragma unroll
  for (int tt = 0; tt < 16; ++tt) {
    ushort hi, lo;
    split2(win, hi, lo);
    ao[(size_t)tt * KK + 512] = hi;
    ao[(size_t)tt * KK + 768] = lo;
    win += hv[16 + tt] - hv[tt];
  }
}

// ---------------------------------------------------------------------------
// Barrier-free split-bf16 MFMA GEMM + bias + tanh.
// Block = 4 independent waves (2x2), each wave owns a 32x32 output tile.
// 8 K-iterations of 64; iter tt: A_hi col = ah*64 (ah = tt<4?tt:tt+4),
// A_lo = +256, W col = tt*64. 3-buffer rotating fragment prefetch (depth 2).
// MODE 0: split C -> Acat2 self segs (j>=16) / h1head (j<16). MODE 1: fp32 C.
// ---------------------------------------------------------------------------
struct Frags { short8 ah[2][2], al[2][2], b1[2][2], b2[2][2]; };  // [mt|nt][ks]

#define LOADF(F, tt)                                                         \
  do {                                                                       \
    constexpr int ahc_ = (((tt) < 4) ? (tt) : ((tt) + 4)) * 64;              \
    constexpr int wc_  = (tt) * 64;                                          \
    _Pragma("unroll") for (int mt = 0; mt < 2; ++mt)                         \
      _Pragma("unroll") for (int ks = 0; ks < 2; ++ks) {                     \
        (F).ah[mt][ks] = *(const short8*)(aB[mt]  + ahc_ + ks * 32);         \
        (F).al[mt][ks] = *(const short8*)(aB[mt]  + ahc_ + 256 + ks * 32);   \
        (F).b1[mt][ks] = *(const short8*)(b1B[mt] + wc_ + ks * 32);          \
        (F).b2[mt][ks] = *(const short8*)(b2B[mt] + wc_ + ks * 32);          \
      }                                                                      \
  } while (0)

#define MFMAF(F)                                                             \
  do {                                                                       \
    _Pragma("unroll") for (int ks = 0; ks < 2; ++ks)                         \
      _Pragma("unroll") for (int mt = 0; mt < 2; ++mt)                       \
        _Pragma("unroll") for (int nt = 0; nt < 2; ++nt) {                   \
          acc[mt][nt] = __builtin_amdgcn_mfma_f32_16x16x32_bf16(             \
              (F).ah[mt][ks], (F).b1[nt][ks], acc[mt][nt], 0, 0, 0);         \
          acc[mt][nt] = __builtin_amdgcn_mfma_f32_16x16x32_bf16(             \
              (F).ah[mt][ks], (F).b2[nt][ks], acc[mt][nt], 0, 0, 0);         \
          acc[mt][nt] = __builtin_amdgcn_mfma_f32_16x16x32_bf16(             \
              (F).al[mt][ks], (F).b1[nt][ks], acc[mt][nt], 0, 0, 0);         \
        }                                                                    \
  } while (0)

template <int MODE>
__global__ __launch_bounds__(256, 2) void gemm_mfma(
    const ushort* __restrict__ A, const ushort* __restrict__ W1,
    const ushort* __restrict__ W2, const float* __restrict__ bias,
    ushort* __restrict__ Acat2, ushort* __restrict__ h1hhi,
    ushort* __restrict__ h1hlo, float* __restrict__ out) {
  const int t = threadIdx.x;
  const int wave = t >> 6, lane = t & 63;
  const int lr = lane & 15, kg = lane >> 4;
  const int m0 = blockIdx.x * 64 + (wave >> 1) * 32;   // wave-tile origin
  const int n0 = blockIdx.y * 64 + (wave & 1) * 32;

  const ushort* aB[2];
  const ushort* b1B[2];
  const ushort* b2B[2];
  #pragma unroll
  for (int i = 0; i < 2; ++i) {
    aB[i]  = A  + (size_t)(m0 + i * 16 + lr) * KK + kg * 8;
    b1B[i] = W1 + (size_t)(n0 + i * 16 + lr) * KW + kg * 8;
    b2B[i] = W2 + (size_t)(n0 + i * 16 + lr) * KW + kg * 8;
  }

  f32x4 acc[2][2] = {};
  Frags f0, f1, f2;
  LOADF(f0, 0);
  LOADF(f1, 1);
  LOADF(f2, 2); MFMAF(f0);
  LOADF(f0, 3); MFMAF(f1);
  LOADF(f1, 4); MFMAF(f2);
  LOADF(f2, 5); MFMAF(f0);
  LOADF(f0, 6); MFMAF(f1);
  LOADF(f1, 7); MFMAF(f2);
  MFMAF(f0);
  MFMAF(f1);

  // epilogue: bias + tanh
  float bv[2];
  #pragma unroll
  for (int nt = 0; nt < 2; ++nt) bv[nt] = bias[n0 + nt * 16 + lr];

  #pragma unroll
  for (int mt = 0; mt < 2; ++mt)
    #pragma unroll
    for (int nt = 0; nt < 2; ++nt)
      #pragma unroll
      for (int r = 0; r < 4; ++r) {
        const int row = m0 + mt * 16 + kg * 4 + r;
        const int col = n0 + nt * 16 + lr;
        const float vv = tanhf(acc[mt][nt][r] + bv[nt]);
        if constexpr (MODE == 0) {
          const int b = row / M1, j = row % M1;     // row = b*144 + j
          ushort hi, lo;
          split2(vv, hi, lo);
          if (j >= 16) {
            const size_t o = (size_t)(b * M2 + (j - 16)) * KK + col;
            Acat2[o]       = hi;
            Acat2[o + 256] = lo;
          } else {
            const size_t o = (size_t)(b * 16 + j) * FEATC + col;
            h1hhi[o] = hi;
            h1hlo[o] = lo;
          }
        } else {
          out[(size_t)row * FEATC + col] = vv;
        }
      }
}

}  // namespace

extern "C" void kernel_launch(void* const* d_in, const int* in_sizes, int n_in,
                              void* d_out, int out_size, void* d_ws, size_t ws_size,
                              hipStream_t stream) {
  const float* x     = (const float*)d_in[0];
  const float* nodes = (const float*)d_in[1];
  // d_in[2] = edge_weight: forward value ew/ew == 1.0 -> unused.
  const float* W1s = (const float*)d_in[3];
  const float* W1n = (const float*)d_in[4];
  const float* b1  = (const float*)d_in[5];
  const float* W2s = (const float*)d_in[6];
  const float* W2n = (const float*)d_in[7];
  const float* b2  = (const float*)d_in[8];
  float* out = (float*)d_out;

  // workspace (ushort elems) — 37,748,736 B total (== R5 footprint, fits)
  const size_t acat1_sz = (size_t)BQ * M1 * KK;      // 9,437,184
  const size_t acat2_sz = (size_t)BQ * M2 * KK;      // 8,388,608
  const size_t head_sz  = (size_t)BQ * 16 * FEATC;   // 262,144
  const size_t w_sz     = (size_t)FEATC * KW;        // 131,072
  const size_t need = (acat1_sz + acat2_sz + 2 * head_sz + 4 * w_sz) * sizeof(ushort);
  if (ws_size < need) return;

  ushort* p = (ushort*)d_ws;
  ushort* Acat1 = p; p += acat1_sz;
  ushort* Acat2 = p; p += acat2_sz;
  ushort* h1hhi = p; p += head_sz;
  ushort* h1hlo = p; p += head_sz;
  ushort* W1_1  = p; p += w_sz;
  ushort* W2_1  = p; p += w_sz;
  ushort* W1_2  = p; p += w_sz;
  ushort* W2_2  = p; p += w_sz;

  prep_fused<<<640, 256, 0, stream>>>(x, nodes, W1s, W1n, W2s, W2n,
                                      Acat1, W1_1, W2_1, W1_2, W2_2);
  gemm_mfma<0><<<dim3((BQ * M1) / 64, FEATC / 64), 256, 0, stream>>>(
      Acat1, W1_1, W2_1, b1, Acat2, h1hhi, h1hlo, nullptr);
  prep2_kernel<<<dim3(BQ, 8), 256, 0, stream>>>(h1hhi, h1hlo, Acat2);
  gemm_mfma<1><<<dim3((BQ * M2) / 64, FEATC / 64), 256, 0, stream>>>(
      Acat2, W1_2, W2_2, b2, nullptr, nullptr, nullptr, out);
}

// Round 7
// 55.803 us; speedup vs baseline: 1.7823x; 1.7823x over previous
//
#include <hip/hip_runtime.h>
#include <hip/hip_bf16.h>

// SparseGCM: 2-layer causal-window GCN on MI355X — split-bf16, fragment-
// contiguous layout, inline-asm prefetch-pipelined MFMA GEMM.
//
// Edges are j->i for j in [i-16,i) per batch, weights normalize to 1.0 ->
// "gather+segment_sum" == 16-wide sliding-window sum. Only outputs i in
// [512,640) matter: layer1 computes i in [496,640).
//
// Precision (R2/R4): single-bf16 fails (correlated L1 errors x16-amplified by
// the L2 window sum). Split v = hi+lo bf16; compute Ahi*Whi + Ahi*Wlo +
// Alo*Whi (3 MFMAs) ~= fp32. Validated R5/R6 (absmax 0.0039).
//
// Perf (R5/R6): both died from zero memory-level parallelism (R5: barrier
// drains vmcnt(0) per iter; R6: compiler sank the prefetch, VGPR=40, serial
// ~700-cyc loads). R7: (a) A/W stored in MFMA-fragment order so each wave
// load is ONE contiguous 1KB global_load_dwordx4; (b) loads issued by inline
// asm (volatile => order kept), 4 rotating buffers, depth-3 prefetch, counted
// s_waitcnt vmcnt(24) + sched_barrier(0) fences. No LDS, no barriers.

namespace {

constexpr int BQ    = 64;
constexpr int FEATC = 256;
constexpr int M1 = 144;   // layer-1 rows/batch: i in [496,640)
constexpr int M2 = 128;   // layer-2 rows/batch: i in [512,640)

using ushort = unsigned short;
using short8 = __attribute__((ext_vector_type(8))) short;   // 8 bf16
using f32x4  = __attribute__((ext_vector_type(4))) float;

__device__ __forceinline__ ushort f2bf(float f) {  // RNE
  union { float f; unsigned u; } v{f};
  unsigned r = v.u + 0x7FFFu + ((v.u >> 16) & 1u);
  return (ushort)(r >> 16);
}
__device__ __forceinline__ float bf2f(ushort h) {
  union { unsigned u; float f; } v{(unsigned)h << 16};
  return v.f;
}
__device__ __forceinline__ void split2(float v, ushort& hi, ushort& lo) {
  hi = f2bf(v);
  lo = f2bf(v - bf2f(hi));
}

// Fragment-contiguous index. Logical row r, packed k in [0,512)
// ([self 256 | win 256] for A; [Wself 256 | Wnbr 256] for W), s = hi(0)/lo(1)
// (for W: s = W1(0)/W2(1)). Storage: [r>>4][k>>5][s][lane][e] with
// lane = (r&15) + 16*((k>>3)&3), e = k&7  ->  a wave's MFMA fragment is the
// contiguous 1KB block at ((rg*16+kb)*2+s)*512.
__device__ __forceinline__ size_t frag_idx(int row, int k, int s) {
  return ((size_t)(((row >> 4) * 16 + (k >> 5)) * 2 + s)) * 512
       + ((k >> 3) & 3) * 128 + (row & 15) * 8 + (k & 7);
}

// ---------------------------------------------------------------------------
// prep_fused: blocks [0,576) = prep1; blocks [576,640) = weight transpose.
// ---------------------------------------------------------------------------
__global__ __launch_bounds__(256) void prep_fused(
    const float* __restrict__ x, const float* __restrict__ nodes,
    const float* __restrict__ W1s, const float* __restrict__ W1n,
    const float* __restrict__ W2s, const float* __restrict__ W2n,
    ushort* __restrict__ A1F, ushort* __restrict__ WF1,
    ushort* __restrict__ WF2) {
  __shared__ float tile[64][65];
  const int blk = blockIdx.x;
  if (blk < 576) {
    const int b = blk / 9, c = blk % 9, f = threadIdx.x;
    const int t0 = c * 16, i0 = 496 + t0;
    const float* nb = nodes + ((size_t)b * 640) * FEATC + f;
    const float* xb = x     + ((size_t)b * 128) * FEATC + f;

    float v[32];
    #pragma unroll
    for (int d = 0; d < 32; ++d) {
      const int i = i0 - 16 + d;
      v[d] = (i < 512) ? nb[(size_t)i * FEATC] : xb[(size_t)(i - 512) * FEATC];
    }
    float win = 0.f;
    #pragma unroll
    for (int d = 0; d < 16; ++d) win += v[d];

    const int row0 = b * M1 + t0;
    #pragma unroll
    for (int tt = 0; tt < 16; ++tt) {
      const int row = row0 + tt;
      ushort hi, lo;
      split2(v[16 + tt], hi, lo);
      A1F[frag_idx(row, f, 0)] = hi;
      A1F[frag_idx(row, f, 1)] = lo;
      split2(win, hi, lo);
      A1F[frag_idx(row, 256 + f, 0)] = hi;
      A1F[frag_idx(row, 256 + f, 1)] = lo;
      win += v[16 + tt] - v[tt];
    }
  } else {
    const int w = blk - 576;
    const int z = w >> 4, rem = w & 15;
    const int k0 = (rem >> 2) * 64, n0 = (rem & 3) * 64;
    const float* src = (z == 0) ? W1s : (z == 1) ? W1n : (z == 2) ? W2s : W2n;
    ushort* dst = (z < 2) ? WF1 : WF2;
    const int koff = (z & 1) * 256;
    const int c = threadIdx.x & 63, r4 = threadIdx.x >> 6;
    #pragma unroll
    for (int p = 0; p < 16; ++p) {
      const int k = r4 + p * 4;
      tile[k][c] = src[(size_t)(k0 + k) * FEATC + n0 + c];
    }
    __syncthreads();
    #pragma unroll
    for (int p = 0; p < 16; ++p) {
      const int n = r4 + p * 4;
      ushort hi, lo;
      split2(tile[c][n], hi, lo);
      dst[frag_idx(n0 + n, koff + k0 + c, 0)] = hi;   // W1 (hi) slot
      dst[frag_idx(n0 + n, koff + k0 + c, 1)] = lo;   // W2 (lo) slot
    }
  }
}

// ---------------------------------------------------------------------------
// prep2: fill window segments of A2F (self segs written by gemm1 epilogue).
// h1 row j (i=496+j): j<16 in h1head{hi,lo}[b*16+j][f]; j>=16 at A2F row
// b*128+(j-16), k=f. Output t: window = h1 rows [t, t+16).
// ---------------------------------------------------------------------------
__global__ __launch_bounds__(256) void prep2_kernel(
    const ushort* __restrict__ h1hhi, const ushort* __restrict__ h1hlo,
    ushort* __restrict__ A2F) {
  const int b = blockIdx.x, c = blockIdx.y, f = threadIdx.x;
  const int t0 = c * 16;

  float hv[32];
  #pragma unroll
  for (int d = 0; d < 32; ++d) {
    const int j = t0 + d;
    if (j < 16) {
      const size_t o = (size_t)(b * 16 + j) * FEATC + f;
      hv[d] = bf2f(h1hhi[o]) + bf2f(h1hlo[o]);
    } else {
      const int r2 = b * M2 + (j - 16);
      hv[d] = bf2f(A2F[frag_idx(r2, f, 0)]) + bf2f(A2F[frag_idx(r2, f, 1)]);
    }
  }
  float win = 0.f;
  #pragma unroll
  for (int d = 0; d < 16; ++d) win += hv[d];

  #pragma unroll
  for (int tt = 0; tt < 16; ++tt) {
    const int r2 = b * M2 + t0 + tt;
    ushort hi, lo;
    split2(win, hi, lo);
    A2F[frag_idx(r2, 256 + f, 0)] = hi;
    A2F[frag_idx(r2, 256 + f, 1)] = lo;
    win += hv[16 + tt] - hv[tt];
  }
}

// ---------------------------------------------------------------------------
// Pipelined split-bf16 MFMA GEMM + bias + tanh (no LDS, no barriers).
// Block = 4 independent waves (2x2); wave tile 32x32; 16 K-steps of 32.
// Depth-3 asm prefetch: 4 rotating buffers, counted vmcnt, sched_barrier.
// MODE 0: split C -> A2F self segs (j>=16) / h1head (j<16). MODE 1: fp32 C.
// ---------------------------------------------------------------------------
struct FB { short8 ah0, ah1, al0, al1, b10, b11, b20, b21; };

#define GLOAD(dst, ptr)                                                      \
  asm volatile("global_load_dwordx4 %0, %1, off"                             \
               : "=v"(dst) : "v"(ptr) : "memory")

#define LOADI(Q, tt) do {                                                    \
  GLOAD(Q.ah0, baseA00 + (tt) * 1024);                                       \
  GLOAD(Q.ah1, baseA10 + (tt) * 1024);                                       \
  GLOAD(Q.al0, baseA01 + (tt) * 1024);                                       \
  GLOAD(Q.al1, baseA11 + (tt) * 1024);                                       \
  GLOAD(Q.b10, baseW0h + (tt) * 1024);                                       \
  GLOAD(Q.b11, baseW1h + (tt) * 1024);                                       \
  GLOAD(Q.b20, baseW0l + (tt) * 1024);                                       \
  GLOAD(Q.b21, baseW1l + (tt) * 1024);                                       \
} while (0)

#define WAITV(n) do {                                                        \
  asm volatile("s_waitcnt vmcnt(" #n ")" ::: "memory");                      \
  __builtin_amdgcn_sched_barrier(0);                                         \
} while (0)

#define MF(a, b, c) c = __builtin_amdgcn_mfma_f32_16x16x32_bf16(a, b, c, 0, 0, 0)

#define COMP(Q) do {                                                         \
  MF(Q.ah0, Q.b10, acc00); MF(Q.ah0, Q.b11, acc01);                          \
  MF(Q.ah1, Q.b10, acc10); MF(Q.ah1, Q.b11, acc11);                          \
  MF(Q.ah0, Q.b20, acc00); MF(Q.ah0, Q.b21, acc01);                          \
  MF(Q.ah1, Q.b20, acc10); MF(Q.ah1, Q.b21, acc11);                          \
  MF(Q.al0, Q.b10, acc00); MF(Q.al0, Q.b11, acc01);                          \
  MF(Q.al1, Q.b10, acc10); MF(Q.al1, Q.b11, acc11);                          \
  __builtin_amdgcn_sched_barrier(0);                                         \
} while (0)

template <int MODE>
__global__ __launch_bounds__(256, 2) void gemm_mfma(
    const ushort* __restrict__ A, const ushort* __restrict__ W,
    const float* __restrict__ bias,
    ushort* __restrict__ A2F, ushort* __restrict__ h1hhi,
    ushort* __restrict__ h1hlo, float* __restrict__ out) {
  const int t = threadIdx.x;
  const int wave = t >> 6, lane = t & 63;
  const int lr = lane & 15, kg = lane >> 4;
  const int m0 = blockIdx.x * 64 + (wave >> 1) * 32;
  const int n0 = blockIdx.y * 64 + (wave & 1) * 32;
  const int rg0 = m0 >> 4, ng0 = n0 >> 4;

  const ushort* baseA00 = A + ((size_t)((rg0 + 0) * 32 + 0)) * 512 + lane * 8;
  const ushort* baseA01 = A + ((size_t)((rg0 + 0) * 32 + 1)) * 512 + lane * 8;
  const ushort* baseA10 = A + ((size_t)((rg0 + 1) * 32 + 0)) * 512 + lane * 8;
  const ushort* baseA11 = A + ((size_t)((rg0 + 1) * 32 + 1)) * 512 + lane * 8;
  const ushort* baseW0h = W + ((size_t)((ng0 + 0) * 32 + 0)) * 512 + lane * 8;
  const ushort* baseW0l = W + ((size_t)((ng0 + 0) * 32 + 1)) * 512 + lane * 8;
  const ushort* baseW1h = W + ((size_t)((ng0 + 1) * 32 + 0)) * 512 + lane * 8;
  const ushort* baseW1l = W + ((size_t)((ng0 + 1) * 32 + 1)) * 512 + lane * 8;

  f32x4 acc00 = {}, acc01 = {}, acc10 = {}, acc11 = {};
  FB q0, q1, q2, q3;

  LOADI(q0, 0); LOADI(q1, 1); LOADI(q2, 2);
  LOADI(q3, 3);  WAITV(24); COMP(q0);
  LOADI(q0, 4);  WAITV(24); COMP(q1);
  LOADI(q1, 5);  WAITV(24); COMP(q2);
  LOADI(q2, 6);  WAITV(24); COMP(q3);
  LOADI(q3, 7);  WAITV(24); COMP(q0);
  LOADI(q0, 8);  WAITV(24); COMP(q1);
  LOADI(q1, 9);  WAITV(24); COMP(q2);
  LOADI(q2, 10); WAITV(24); COMP(q3);
  LOADI(q3, 11); WAITV(24); COMP(q0);
  LOADI(q0, 12); WAITV(24); COMP(q1);
  LOADI(q1, 13); WAITV(24); COMP(q2);
  LOADI(q2, 14); WAITV(24); COMP(q3);
  LOADI(q3, 15); WAITV(24); COMP(q0);
  WAITV(16); COMP(q1);
  WAITV(8);  COMP(q2);
  WAITV(0);  COMP(q3);

  // epilogue: bias + tanh
  const float bv0 = bias[n0 + lr];
  const float bv1 = bias[n0 + 16 + lr];

  auto epi = [&](const f32x4& a, int mt, int nt, float bv) {
    #pragma unroll
    for (int r = 0; r < 4; ++r) {
      const int row = m0 + mt * 16 + kg * 4 + r;
      const int col = n0 + nt * 16 + lr;
      const float vv = tanhf(a[r] + bv);
      if constexpr (MODE == 0) {
        const int b = row / M1, j = row % M1;       // row = b*144 + j
        ushort hi, lo;
        split2(vv, hi, lo);
        if (j >= 16) {
          const int r2 = b * M2 + (j - 16);
          A2F[frag_idx(r2, col, 0)] = hi;
          A2F[frag_idx(r2, col, 1)] = lo;
        } else {
          const size_t o = (size_t)(b * 16 + j) * FEATC + col;
          h1hhi[o] = hi;
          h1hlo[o] = lo;
        }
      } else {
        out[(size_t)row * FEATC + col] = vv;
      }
    }
  };
  epi(acc00, 0, 0, bv0);
  epi(acc01, 0, 1, bv1);
  epi(acc10, 1, 0, bv0);
  epi(acc11, 1, 1, bv1);
}

}  // namespace

extern "C" void kernel_launch(void* const* d_in, const int* in_sizes, int n_in,
                              void* d_out, int out_size, void* d_ws, size_t ws_size,
                              hipStream_t stream) {
  const float* x     = (const float*)d_in[0];
  const float* nodes = (const float*)d_in[1];
  // d_in[2] = edge_weight: forward value ew/ew == 1.0 -> unused.
  const float* W1s = (const float*)d_in[3];
  const float* W1n = (const float*)d_in[4];
  const float* b1  = (const float*)d_in[5];
  const float* W2s = (const float*)d_in[6];
  const float* W2n = (const float*)d_in[7];
  const float* b2  = (const float*)d_in[8];
  float* out = (float*)d_out;

  // workspace (ushort elems) — 37,748,736 B total (same as R5/R6, fits)
  const size_t a1_sz   = (size_t)BQ * M1 * 1024;     // 9,437,184
  const size_t a2_sz   = (size_t)BQ * M2 * 1024;     // 8,388,608
  const size_t head_sz = (size_t)BQ * 16 * FEATC;    // 262,144
  const size_t wf_sz   = (size_t)16 * 16 * 2 * 512;  // 262,144 (per layer)
  const size_t need = (a1_sz + a2_sz + 2 * head_sz + 2 * wf_sz) * sizeof(ushort);
  if (ws_size < need) return;

  ushort* p = (ushort*)d_ws;
  ushort* A1F   = p; p += a1_sz;
  ushort* A2F   = p; p += a2_sz;
  ushort* h1hhi = p; p += head_sz;
  ushort* h1hlo = p; p += head_sz;
  ushort* WF1   = p; p += wf_sz;
  ushort* WF2   = p; p += wf_sz;

  prep_fused<<<640, 256, 0, stream>>>(x, nodes, W1s, W1n, W2s, W2n,
                                      A1F, WF1, WF2);
  gemm_mfma<0><<<dim3((BQ * M1) / 64, FEATC / 64), 256, 0, stream>>>(
      A1F, WF1, b1, A2F, h1hhi, h1hlo, nullptr);
  prep2_kernel<<<dim3(BQ, 8), 256, 0, stream>>>(h1hhi, h1hlo, A2F);
  gemm_mfma<1><<<dim3((BQ * M2) / 64, FEATC / 64), 256, 0, stream>>>(
      A2F, WF2, b2, nullptr, nullptr, nullptr, out);
}

// Round 8
// 49.705 us; speedup vs baseline: 2.0009x; 1.1227x over previous
//
#include <hip/hip_runtime.h>
#include <hip/hip_bf16.h>

// SparseGCM: 2-layer causal-window GCN on MI355X — split-bf16, fragment-
// contiguous layout, inline-asm depth-4 prefetch MFMA GEMM, burst-write preps.
//
// Edges are j->i for j in [i-16,i) per batch, weights normalize to 1.0 ->
// "gather+segment_sum" == 16-wide sliding-window sum. Only outputs i in
// [512,640) matter: layer1 computes i in [496,640).
//
// Precision (R2/R4): single-bf16 fails (correlated L1 errors x16-amplified by
// the L2 window sum). Split v = hi+lo bf16; compute Ahi*Whi + Ahi*Wlo +
// Alo*Whi (3 MFMAs) ~= fp32. Validated R5/R6/R7 (absmax 0.0039).
//
// Perf history: R5 LDS 2-phase (barrier drains vmcnt0) 61.2; R6 compiler ate
// the reg pipeline 99.5; R7 asm depth-3 pipeline + frag layout 55.8.
// R8: (a) depth-4 (40 loads in flight, vmcnt(32)); (b) all prep/epilogue
// global writes are linear 16B bursts via LDS transpose staging — gemm1 now
// writes plain row-major f32 h1, prep2 rebuilds self+win frag segments.

namespace {

constexpr int BQ    = 64;
constexpr int FEATC = 256;
constexpr int M1 = 144;   // layer-1 rows/batch: i in [496,640)
constexpr int M2 = 128;   // layer-2 rows/batch: i in [512,640)

using ushort = unsigned short;
using short8 = __attribute__((ext_vector_type(8))) short;   // 8 bf16
using f32x4  = __attribute__((ext_vector_type(4))) float;

__device__ __forceinline__ ushort f2bf(float f) {  // RNE
  union { float f; unsigned u; } v{f};
  unsigned r = v.u + 0x7FFFu + ((v.u >> 16) & 1u);
  return (ushort)(r >> 16);
}
__device__ __forceinline__ float bf2f(ushort h) {
  union { unsigned u; float f; } v{(unsigned)h << 16};
  return v.f;
}
__device__ __forceinline__ void split2(float v, ushort& hi, ushort& lo) {
  hi = f2bf(v);
  lo = f2bf(v - bf2f(hi));
}

// Fragment-contiguous layout. Row r, packed k in [0,512) ([self|win] for A,
// [Wself|Wnbr] for W), s = hi(0)/lo(1) (for W: W1/W2). A wave's MFMA fragment
// = contiguous 1KB block at ((rg*16 + kb)*2 + s)*512, lane-linear inside.
__device__ __forceinline__ size_t frag_idx(int row, int k, int s) {
  return ((size_t)(((row >> 4) * 16 + (k >> 5)) * 2 + s)) * 512
       + ((k >> 3) & 3) * 128 + (row & 15) * 8 + (k & 7);
}
// Same, local to one 16-row group (16384-elem block).
__device__ __forceinline__ int lofs(int row_l, int k, int s) {
  return ((k >> 5) * 2 + s) * 512 + ((k >> 3) & 3) * 128 + row_l * 8 + (k & 7);
}

// ---------------------------------------------------------------------------
// prep_fused: blocks [0,576) = prep1 (A1F via LDS burst);
//             blocks [576,640) = weight transpose+split (small, scattered ok).
// ---------------------------------------------------------------------------
__global__ __launch_bounds__(256) void prep_fused(
    const float* __restrict__ x, const float* __restrict__ nodes,
    const float* __restrict__ W1s, const float* __restrict__ W1n,
    const float* __restrict__ W2s, const float* __restrict__ W2n,
    ushort* __restrict__ A1F, ushort* __restrict__ WF1,
    ushort* __restrict__ WF2) {
  __shared__ ushort lds_o[16384];   // one 16-row frag group (32 KB)
  __shared__ float tile[64][65];
  const int blk = blockIdx.x;
  if (blk < 576) {
    const int b = blk / 9, c = blk % 9, f = threadIdx.x;
    const int t0 = c * 16, i0 = 496 + t0;
    const float* nb = nodes + ((size_t)b * 640) * FEATC + f;
    const float* xb = x     + ((size_t)b * 128) * FEATC + f;

    float v[32];
    #pragma unroll
    for (int d = 0; d < 32; ++d) {
      const int i = i0 - 16 + d;
      v[d] = (i < 512) ? nb[(size_t)i * FEATC] : xb[(size_t)(i - 512) * FEATC];
    }
    float win = 0.f;
    #pragma unroll
    for (int d = 0; d < 16; ++d) win += v[d];

    #pragma unroll
    for (int tt = 0; tt < 16; ++tt) {
      ushort hi, lo;
      split2(v[16 + tt], hi, lo);
      lds_o[lofs(tt, f, 0)] = hi;
      lds_o[lofs(tt, f, 1)] = lo;
      split2(win, hi, lo);
      lds_o[lofs(tt, 256 + f, 0)] = hi;
      lds_o[lofs(tt, 256 + f, 1)] = lo;
      win += v[16 + tt] - v[tt];
    }
    __syncthreads();
    ushort* dst = A1F + (size_t)(b * 9 + c) * 16384;
    #pragma unroll
    for (int it = 0; it < 8; ++it) {
      const int idx = it * 256 + threadIdx.x;
      *(short8*)(dst + idx * 8) = *(const short8*)(lds_o + idx * 8);
    }
  } else {
    const int w = blk - 576;
    const int z = w >> 4, rem = w & 15;
    const int k0 = (rem >> 2) * 64, n0 = (rem & 3) * 64;
    const float* src = (z == 0) ? W1s : (z == 1) ? W1n : (z == 2) ? W2s : W2n;
    ushort* dst = (z < 2) ? WF1 : WF2;
    const int koff = (z & 1) * 256;
    const int c = threadIdx.x & 63, r4 = threadIdx.x >> 6;
    #pragma unroll
    for (int p = 0; p < 16; ++p) {
      const int k = r4 + p * 4;
      tile[k][c] = src[(size_t)(k0 + k) * FEATC + n0 + c];
    }
    __syncthreads();
    #pragma unroll
    for (int p = 0; p < 16; ++p) {
      const int n = r4 + p * 4;
      ushort hi, lo;
      split2(tile[c][n], hi, lo);
      dst[frag_idx(n0 + n, koff + k0 + c, 0)] = hi;   // W1 (hi) slot
      dst[frag_idx(n0 + n, koff + k0 + c, 1)] = lo;   // W2 (lo) slot
    }
  }
}

// ---------------------------------------------------------------------------
// prep2: build A2F (both self and window frag segments) from row-major h1f32.
// Block (b,c): output rows r2 = b*128 + c*16 + tt; self = h1 row t+16,
// window = sum h1 rows [t, t+16), t = c*16+tt. Reads 32 h1 rows coalesced,
// writes one contiguous 32 KB frag group.
// ---------------------------------------------------------------------------
__global__ __launch_bounds__(256) void prep2_kernel(
    const float* __restrict__ h1f32, ushort* __restrict__ A2F) {
  __shared__ ushort lds_o[16384];
  const int b = blockIdx.x, c = blockIdx.y, f = threadIdx.x;
  const int t0 = c * 16;
  const float* hp = h1f32 + ((size_t)(b * M1 + t0)) * FEATC + f;

  float hv[32];
  #pragma unroll
  for (int d = 0; d < 32; ++d) hv[d] = hp[(size_t)d * FEATC];
  float win = 0.f;
  #pragma unroll
  for (int d = 0; d < 16; ++d) win += hv[d];

  #pragma unroll
  for (int tt = 0; tt < 16; ++tt) {
    ushort hi, lo;
    split2(hv[16 + tt], hi, lo);          // self = h1 row t+16
    lds_o[lofs(tt, f, 0)] = hi;
    lds_o[lofs(tt, f, 1)] = lo;
    split2(win, hi, lo);                  // window sum [t, t+16)
    lds_o[lofs(tt, 256 + f, 0)] = hi;
    lds_o[lofs(tt, 256 + f, 1)] = lo;
    win += hv[16 + tt] - hv[tt];
  }
  __syncthreads();
  ushort* dst = A2F + (size_t)(b * 8 + c) * 16384;
  #pragma unroll
  for (int it = 0; it < 8; ++it) {
    const int idx = it * 256 + threadIdx.x;
    *(short8*)(dst + idx * 8) = *(const short8*)(lds_o + idx * 8);
  }
}

// ---------------------------------------------------------------------------
// Depth-4 asm-pipelined split-bf16 MFMA GEMM + bias + tanh (no LDS/barriers).
// Block = 4 independent waves (2x2); wave tile 32x32; 16 K-steps of 32.
// 5 rotating buffers, 40 loads in flight, steady s_waitcnt vmcnt(32).
// Output: plain row-major f32 [M][256].
// ---------------------------------------------------------------------------
struct FB { short8 ah0, ah1, al0, al1, b10, b11, b20, b21; };

#define GLOAD(dst, ptr)                                                      \
  asm volatile("global_load_dwordx4 %0, %1, off"                             \
               : "=v"(dst) : "v"(ptr) : "memory")

#define LOADI(Q, tt) do {                                                    \
  GLOAD(Q.ah0, baseA00 + (tt) * 1024);                                       \
  GLOAD(Q.ah1, baseA10 + (tt) * 1024);                                       \
  GLOAD(Q.al0, baseA01 + (tt) * 1024);                                       \
  GLOAD(Q.al1, baseA11 + (tt) * 1024);                                       \
  GLOAD(Q.b10, baseW0h + (tt) * 1024);                                       \
  GLOAD(Q.b11, baseW1h + (tt) * 1024);                                       \
  GLOAD(Q.b20, baseW0l + (tt) * 1024);                                       \
  GLOAD(Q.b21, baseW1l + (tt) * 1024);                                       \
} while (0)

#define WAITV(n) do {                                                        \
  asm volatile("s_waitcnt vmcnt(" #n ")" ::: "memory");                      \
  __builtin_amdgcn_sched_barrier(0);                                         \
} while (0)

#define MF(a, b, c) c = __builtin_amdgcn_mfma_f32_16x16x32_bf16(a, b, c, 0, 0, 0)

#define COMP(Q) do {                                                         \
  MF(Q.ah0, Q.b10, acc00); MF(Q.ah0, Q.b11, acc01);                          \
  MF(Q.ah1, Q.b10, acc10); MF(Q.ah1, Q.b11, acc11);                          \
  MF(Q.ah0, Q.b20, acc00); MF(Q.ah0, Q.b21, acc01);                          \
  MF(Q.ah1, Q.b20, acc10); MF(Q.ah1, Q.b21, acc11);                          \
  MF(Q.al0, Q.b10, acc00); MF(Q.al0, Q.b11, acc01);                          \
  MF(Q.al1, Q.b10, acc10); MF(Q.al1, Q.b11, acc11);                          \
  __builtin_amdgcn_sched_barrier(0);                                         \
} while (0)

__global__ __launch_bounds__(256, 2) void gemm_mfma(
    const ushort* __restrict__ A, const ushort* __restrict__ W,
    const float* __restrict__ bias, float* __restrict__ out) {
  const int t = threadIdx.x;
  const int wave = t >> 6, lane = t & 63;
  const int lr = lane & 15, kg = lane >> 4;
  const int m0 = blockIdx.x * 64 + (wave >> 1) * 32;
  const int n0 = blockIdx.y * 64 + (wave & 1) * 32;
  const int rg0 = m0 >> 4, ng0 = n0 >> 4;

  const ushort* baseA00 = A + ((size_t)((rg0 + 0) * 32 + 0)) * 512 + lane * 8;
  const ushort* baseA01 = A + ((size_t)((rg0 + 0) * 32 + 1)) * 512 + lane * 8;
  const ushort* baseA10 = A + ((size_t)((rg0 + 1) * 32 + 0)) * 512 + lane * 8;
  const ushort* baseA11 = A + ((size_t)((rg0 + 1) * 32 + 1)) * 512 + lane * 8;
  const ushort* baseW0h = W + ((size_t)((ng0 + 0) * 32 + 0)) * 512 + lane * 8;
  const ushort* baseW0l = W + ((size_t)((ng0 + 0) * 32 + 1)) * 512 + lane * 8;
  const ushort* baseW1h = W + ((size_t)((ng0 + 1) * 32 + 0)) * 512 + lane * 8;
  const ushort* baseW1l = W + ((size_t)((ng0 + 1) * 32 + 1)) * 512 + lane * 8;

  f32x4 acc00 = {}, acc01 = {}, acc10 = {}, acc11 = {};
  FB q0, q1, q2, q3, q4;

  LOADI(q0, 0); LOADI(q1, 1); LOADI(q2, 2); LOADI(q3, 3); LOADI(q4, 4);
  WAITV(32); COMP(q0); LOADI(q0, 5);
  WAITV(32); COMP(q1); LOADI(q1, 6);
  WAITV(32); COMP(q2); LOADI(q2, 7);
  WAITV(32); COMP(q3); LOADI(q3, 8);
  WAITV(32); COMP(q4); LOADI(q4, 9);
  WAITV(32); COMP(q0); LOADI(q0, 10);
  WAITV(32); COMP(q1); LOADI(q1, 11);
  WAITV(32); COMP(q2); LOADI(q2, 12);
  WAITV(32); COMP(q3); LOADI(q3, 13);
  WAITV(32); COMP(q4); LOADI(q4, 14);
  WAITV(32); COMP(q0); LOADI(q0, 15);
  WAITV(32); COMP(q1);
  WAITV(24); COMP(q2);
  WAITV(16); COMP(q3);
  WAITV(8);  COMP(q4);
  WAITV(0);  COMP(q0);

  // epilogue: bias + tanh, row-major f32 out
  const float bv0 = bias[n0 + lr];
  const float bv1 = bias[n0 + 16 + lr];
  auto epi = [&](const f32x4& a, int mt, int nt, float bv) {
    #pragma unroll
    for (int r = 0; r < 4; ++r) {
      const int row = m0 + mt * 16 + kg * 4 + r;
      const int col = n0 + nt * 16 + lr;
      out[(size_t)row * FEATC + col] = tanhf(a[r] + bv);
    }
  };
  epi(acc00, 0, 0, bv0);
  epi(acc01, 0, 1, bv1);
  epi(acc10, 1, 0, bv0);
  epi(acc11, 1, 1, bv1);
}

}  // namespace

extern "C" void kernel_launch(void* const* d_in, const int* in_sizes, int n_in,
                              void* d_out, int out_size, void* d_ws, size_t ws_size,
                              hipStream_t stream) {
  const float* x     = (const float*)d_in[0];
  const float* nodes = (const float*)d_in[1];
  // d_in[2] = edge_weight: forward value ew/ew == 1.0 -> unused.
  const float* W1s = (const float*)d_in[3];
  const float* W1n = (const float*)d_in[4];
  const float* b1  = (const float*)d_in[5];
  const float* W2s = (const float*)d_in[6];
  const float* W2n = (const float*)d_in[7];
  const float* b2  = (const float*)d_in[8];
  float* out = (float*)d_out;

  // workspace: ushort region then f32 region (46.1 MB total)
  const size_t a1_sz = (size_t)BQ * M1 * 1024;      // 9,437,184 us
  const size_t a2_sz = (size_t)BQ * M2 * 1024;      // 8,388,608 us
  const size_t wf_sz = (size_t)16 * 16 * 2 * 512;   // 262,144 us per layer
  const size_t us_total = a1_sz + a2_sz + 2 * wf_sz;
  const size_t h1_sz = (size_t)BQ * M1 * FEATC;     // 2,359,296 f32
  const size_t need = us_total * sizeof(ushort) + h1_sz * sizeof(float);
  if (ws_size < need) return;

  ushort* p = (ushort*)d_ws;
  ushort* A1F = p; p += a1_sz;
  ushort* A2F = p; p += a2_sz;
  ushort* WF1 = p; p += wf_sz;
  ushort* WF2 = p; p += wf_sz;
  float* h1f32 = (float*)p;

  prep_fused<<<640, 256, 0, stream>>>(x, nodes, W1s, W1n, W2s, W2n,
                                      A1F, WF1, WF2);
  gemm_mfma<<<dim3((BQ * M1) / 64, FEATC / 64), 256, 0, stream>>>(
      A1F, WF1, b1, h1f32);
  prep2_kernel<<<dim3(BQ, 8), 256, 0, stream>>>(h1f32, A2F);
  gemm_mfma<<<dim3((BQ * M2) / 64, FEATC / 64), 256, 0, stream>>>(
      A2F, WF2, b2, out);
}

// Round 10
// 47.766 us; speedup vs baseline: 2.0822x; 1.0406x over previous
//
#include <hip/hip_runtime.h>
#include <hip/hip_bf16.h>

// SparseGCM: 2-layer causal-window GCN on MI355X — split-bf16, fragment-
// contiguous layout, inline-asm depth-4 prefetch MFMA GEMM, burst-write preps,
// XCD writer/reader colocation.
//
// Edges are j->i for j in [i-16,i) per batch, weights normalize to 1.0 ->
// "gather+segment_sum" == 16-wide sliding-window sum. Only outputs i in
// [512,640) matter: layer1 computes i in [496,640).
//
// Precision (R2/R4): single-bf16 fails (correlated L1 errors x16-amplified by
// the L2 window sum). Split v = hi+lo bf16; compute Ahi*Whi + Ahi*Wlo +
// Alo*Whi (3 MFMAs) ~= fp32. Validated R5-R8 (absmax 0.0039).
//
// Perf history: R5 61.2; R6 99.5 (compiler ate reg pipeline); R7 55.8 (asm
// depth-3 + frag layout); R8 49.7 (depth-4 + burst writes); R9 fused preps
// into gemm -> ABORT (compiler staging loads interleaved with in-flight asm
// loads corrupt vmcnt bookkeeping — asm-pipelined regions must contain ONLY
// asm vmem). R10 = R8 + XCD colocation: permute prep block->group mapping so
// the XCD that writes each A-group (block_id%8 round-robin) equals the XCD
// of the gemm blocks that read it (gemm grid.x % 8 == 0 makes all N-blocks
// of panel mx land on XCD mx%8). Per-XCD A-slice (2.4/2.1 MB) fits 4MB L2 ->
// A-loads drop ~700cy IF$ -> ~200cy local L2, inside the pipeline's cover.

namespace {

constexpr int BQ    = 64;
constexpr int FEATC = 256;
constexpr int M1 = 144;   // layer-1 rows/batch: i in [496,640)
constexpr int M2 = 128;   // layer-2 rows/batch: i in [512,640)

using ushort = unsigned short;
using short8 = __attribute__((ext_vector_type(8))) short;   // 8 bf16
using f32x4  = __attribute__((ext_vector_type(4))) float;

__device__ __forceinline__ ushort f2bf(float f) {  // RNE
  union { float f; unsigned u; } v{f};
  unsigned r = v.u + 0x7FFFu + ((v.u >> 16) & 1u);
  return (ushort)(r >> 16);
}
__device__ __forceinline__ float bf2f(ushort h) {
  union { unsigned u; float f; } v{(unsigned)h << 16};
  return v.f;
}
__device__ __forceinline__ void split2(float v, ushort& hi, ushort& lo) {
  hi = f2bf(v);
  lo = f2bf(v - bf2f(hi));
}

// Fragment-contiguous layout. Row r, packed k in [0,512) ([self|win] for A,
// [Wself|Wnbr] for W), s = hi(0)/lo(1) (for W: W1/W2). A wave's MFMA fragment
// = contiguous 1KB block at ((rg*16 + kb)*2 + s)*512, lane-linear inside.
__device__ __forceinline__ size_t frag_idx(int row, int k, int s) {
  return ((size_t)(((row >> 4) * 16 + (k >> 5)) * 2 + s)) * 512
       + ((k >> 3) & 3) * 128 + (row & 15) * 8 + (k & 7);
}
// Same, local to one 16-row group (16384-elem block).
__device__ __forceinline__ int lofs(int row_l, int k, int s) {
  return ((k >> 5) * 2 + s) * 512 + ((k >> 3) & 3) * 128 + row_l * 8 + (k & 7);
}

// ---------------------------------------------------------------------------
// prep_fused: blocks [0,576) = prep1 (A1F via LDS burst, XCD-colocated);
//             blocks [576,640) = weight transpose+split.
// XCD colocation: block p handles memory group G = 4*(p%144) + (p/144), so
// writer XCD p%8 == (G/4)%8 == reader gemm1 panel XCD.
// ---------------------------------------------------------------------------
__global__ __launch_bounds__(256) void prep_fused(
    const float* __restrict__ x, const float* __restrict__ nodes,
    const float* __restrict__ W1s, const float* __restrict__ W1n,
    const float* __restrict__ W2s, const float* __restrict__ W2n,
    ushort* __restrict__ A1F, ushort* __restrict__ WF1,
    ushort* __restrict__ WF2) {
  __shared__ ushort lds_o[16384];   // one 16-row frag group (32 KB)
  __shared__ float tile[64][65];
  const int blk = blockIdx.x;
  if (blk < 576) {
    const int G = 4 * (blk % 144) + (blk / 144);   // XCD-colocation permutation
    const int b = G / 9, c = G % 9, f = threadIdx.x;
    const int t0 = c * 16, i0 = 496 + t0;
    const float* nb = nodes + ((size_t)b * 640) * FEATC + f;
    const float* xb = x     + ((size_t)b * 128) * FEATC + f;

    float v[32];
    #pragma unroll
    for (int d = 0; d < 32; ++d) {
      const int i = i0 - 16 + d;
      v[d] = (i < 512) ? nb[(size_t)i * FEATC] : xb[(size_t)(i - 512) * FEATC];
    }
    float win = 0.f;
    #pragma unroll
    for (int d = 0; d < 16; ++d) win += v[d];

    #pragma unroll
    for (int tt = 0; tt < 16; ++tt) {
      ushort hi, lo;
      split2(v[16 + tt], hi, lo);
      lds_o[lofs(tt, f, 0)] = hi;
      lds_o[lofs(tt, f, 1)] = lo;
      split2(win, hi, lo);
      lds_o[lofs(tt, 256 + f, 0)] = hi;
      lds_o[lofs(tt, 256 + f, 1)] = lo;
      win += v[16 + tt] - v[tt];
    }
    __syncthreads();
    ushort* dst = A1F + (size_t)G * 16384;
    #pragma unroll
    for (int it = 0; it < 8; ++it) {
      const int idx = it * 256 + threadIdx.x;
      *(short8*)(dst + idx * 8) = *(const short8*)(lds_o + idx * 8);
    }
  } else {
    const int w = blk - 576;
    const int z = w >> 4, rem = w & 15;
    const int k0 = (rem >> 2) * 64, n0 = (rem & 3) * 64;
    const float* src = (z == 0) ? W1s : (z == 1) ? W1n : (z == 2) ? W2s : W2n;
    ushort* dst = (z < 2) ? WF1 : WF2;
    const int koff = (z & 1) * 256;
    const int c = threadIdx.x & 63, r4 = threadIdx.x >> 6;
    #pragma unroll
    for (int p = 0; p < 16; ++p) {
      const int k = r4 + p * 4;
      tile[k][c] = src[(size_t)(k0 + k) * FEATC + n0 + c];
    }
    __syncthreads();
    #pragma unroll
    for (int p = 0; p < 16; ++p) {
      const int n = r4 + p * 4;
      ushort hi, lo;
      split2(tile[c][n], hi, lo);
      dst[frag_idx(n0 + n, koff + k0 + c, 0)] = hi;   // W1 (hi) slot
      dst[frag_idx(n0 + n, koff + k0 + c, 1)] = lo;   // W2 (lo) slot
    }
  }
}

// ---------------------------------------------------------------------------
// prep2: build A2F (self + window frag segments) from row-major h1f32.
// 1D grid of 512, XCD-colocated: block p handles group G2 = 4*(p%128)+(p/128)
// (writer XCD p%8 == (G2/4)%8 == reader gemm2 panel XCD). Group G2 covers
// output rows r2 = 16*G2 .. +16 (b = G2/8, t0 = (G2%8)*16).
// ---------------------------------------------------------------------------
__global__ __launch_bounds__(256) void prep2_kernel(
    const float* __restrict__ h1f32, ushort* __restrict__ A2F) {
  __shared__ ushort lds_o[16384];
  const int G2 = 4 * ((int)blockIdx.x % 128) + ((int)blockIdx.x / 128);
  const int b = G2 >> 3, c = G2 & 7, f = threadIdx.x;
  const int t0 = c * 16;
  const float* hp = h1f32 + ((size_t)(b * M1 + t0)) * FEATC + f;

  float hv[32];
  #pragma unroll
  for (int d = 0; d < 32; ++d) hv[d] = hp[(size_t)d * FEATC];
  float win = 0.f;
  #pragma unroll
  for (int d = 0; d < 16; ++d) win += hv[d];

  #pragma unroll
  for (int tt = 0; tt < 16; ++tt) {
    ushort hi, lo;
    split2(hv[16 + tt], hi, lo);          // self = h1 row t+16
    lds_o[lofs(tt, f, 0)] = hi;
    lds_o[lofs(tt, f, 1)] = lo;
    split2(win, hi, lo);                  // window sum [t, t+16)
    lds_o[lofs(tt, 256 + f, 0)] = hi;
    lds_o[lofs(tt, 256 + f, 1)] = lo;
    win += hv[16 + tt] - hv[tt];
  }
  __syncthreads();
  ushort* dst = A2F + (size_t)G2 * 16384;
  #pragma unroll
  for (int it = 0; it < 8; ++it) {
    const int idx = it * 256 + threadIdx.x;
    *(short8*)(dst + idx * 8) = *(const short8*)(lds_o + idx * 8);
  }
}

// ---------------------------------------------------------------------------
// Depth-4 asm-pipelined split-bf16 MFMA GEMM + bias + tanh (no LDS/barriers).
// Block = 4 independent waves (2x2); wave tile 32x32; 16 K-steps of 32.
// 5 rotating buffers, 40 loads in flight, steady s_waitcnt vmcnt(32).
// ONLY asm vmem inside the pipelined region (R9 lesson). Row-major f32 out.
// ---------------------------------------------------------------------------
struct FB { short8 ah0, ah1, al0, al1, b10, b11, b20, b21; };

#define GLOAD(dst, ptr)                                                      \
  asm volatile("global_load_dwordx4 %0, %1, off"                             \
               : "=v"(dst) : "v"(ptr) : "memory")

#define LOADI(Q, tt) do {                                                    \
  GLOAD(Q.ah0, baseA00 + (tt) * 1024);                                       \
  GLOAD(Q.ah1, baseA10 + (tt) * 1024);                                       \
  GLOAD(Q.al0, baseA01 + (tt) * 1024);                                       \
  GLOAD(Q.al1, baseA11 + (tt) * 1024);                                       \
  GLOAD(Q.b10, baseW0h + (tt) * 1024);                                       \
  GLOAD(Q.b11, baseW1h + (tt) * 1024);                                       \
  GLOAD(Q.b20, baseW0l + (tt) * 1024);                                       \
  GLOAD(Q.b21, baseW1l + (tt) * 1024);                                       \
} while (0)

#define WAITV(n) do {                                                        \
  asm volatile("s_waitcnt vmcnt(" #n ")" ::: "memory");                      \
  __builtin_amdgcn_sched_barrier(0);                                         \
} while (0)

#define MF(a, b, c) c = __builtin_amdgcn_mfma_f32_16x16x32_bf16(a, b, c, 0, 0, 0)

#define COMP(Q) do {                                                         \
  MF(Q.ah0, Q.b10, acc00); MF(Q.ah0, Q.b11, acc01);                          \
  MF(Q.ah1, Q.b10, acc10); MF(Q.ah1, Q.b11, acc11);                          \
  MF(Q.ah0, Q.b20, acc00); MF(Q.ah0, Q.b21, acc01);                          \
  MF(Q.ah1, Q.b20, acc10); MF(Q.ah1, Q.b21, acc11);                          \
  MF(Q.al0, Q.b10, acc00); MF(Q.al0, Q.b11, acc01);                          \
  MF(Q.al1, Q.b10, acc10); MF(Q.al1, Q.b11, acc11);                          \
  __builtin_amdgcn_sched_barrier(0);                                         \
} while (0)

__global__ __launch_bounds__(256, 2) void gemm_mfma(
    const ushort* __restrict__ A, const ushort* __restrict__ W,
    const float* __restrict__ bias, float* __restrict__ out) {
  const int t = threadIdx.x;
  const int wave = t >> 6, lane = t & 63;
  const int lr = lane & 15, kg = lane >> 4;
  const int m0 = blockIdx.x * 64 + (wave >> 1) * 32;
  const int n0 = blockIdx.y * 64 + (wave & 1) * 32;
  const int rg0 = m0 >> 4, ng0 = n0 >> 4;

  const ushort* baseA00 = A + ((size_t)((rg0 + 0) * 32 + 0)) * 512 + lane * 8;
  const ushort* baseA01 = A + ((size_t)((rg0 + 0) * 32 + 1)) * 512 + lane * 8;
  const ushort* baseA10 = A + ((size_t)((rg0 + 1) * 32 + 0)) * 512 + lane * 8;
  const ushort* baseA11 = A + ((size_t)((rg0 + 1) * 32 + 1)) * 512 + lane * 8;
  const ushort* baseW0h = W + ((size_t)((ng0 + 0) * 32 + 0)) * 512 + lane * 8;
  const ushort* baseW0l = W + ((size_t)((ng0 + 0) * 32 + 1)) * 512 + lane * 8;
  const ushort* baseW1h = W + ((size_t)((ng0 + 1) * 32 + 0)) * 512 + lane * 8;
  const ushort* baseW1l = W + ((size_t)((ng0 + 1) * 32 + 1)) * 512 + lane * 8;

  f32x4 acc00 = {}, acc01 = {}, acc10 = {}, acc11 = {};
  FB q0, q1, q2, q3, q4;

  LOADI(q0, 0); LOADI(q1, 1); LOADI(q2, 2); LOADI(q3, 3); LOADI(q4, 4);
  WAITV(32); COMP(q0); LOADI(q0, 5);
  WAITV(32); COMP(q1); LOADI(q1, 6);
  WAITV(32); COMP(q2); LOADI(q2, 7);
  WAITV(32); COMP(q3); LOADI(q3, 8);
  WAITV(32); COMP(q4); LOADI(q4, 9);
  WAITV(32); COMP(q0); LOADI(q0, 10);
  WAITV(32); COMP(q1); LOADI(q1, 11);
  WAITV(32); COMP(q2); LOADI(q2, 12);
  WAITV(32); COMP(q3); LOADI(q3, 13);
  WAITV(32); COMP(q4); LOADI(q4, 14);
  WAITV(32); COMP(q0); LOADI(q0, 15);
  WAITV(32); COMP(q1);
  WAITV(24); COMP(q2);
  WAITV(16); COMP(q3);
  WAITV(8);  COMP(q4);
  WAITV(0);  COMP(q0);

  // epilogue: bias + tanh, row-major f32 out
  const float bv0 = bias[n0 + lr];
  const float bv1 = bias[n0 + 16 + lr];
  auto epi = [&](const f32x4& a, int mt, int nt, float bv) {
    #pragma unroll
    for (int r = 0; r < 4; ++r) {
      const int row = m0 + mt * 16 + kg * 4 + r;
      const int col = n0 + nt * 16 + lr;
      out[(size_t)row * FEATC + col] = tanhf(a[r] + bv);
    }
  };
  epi(acc00, 0, 0, bv0);
  epi(acc01, 0, 1, bv1);
  epi(acc10, 1, 0, bv0);
  epi(acc11, 1, 1, bv1);
}

}  // namespace

extern "C" void kernel_launch(void* const* d_in, const int* in_sizes, int n_in,
                              void* d_out, int out_size, void* d_ws, size_t ws_size,
                              hipStream_t stream) {
  const float* x     = (const float*)d_in[0];
  const float* nodes = (const float*)d_in[1];
  // d_in[2] = edge_weight: forward value ew/ew == 1.0 -> unused.
  const float* W1s = (const float*)d_in[3];
  const float* W1n = (const float*)d_in[4];
  const float* b1  = (const float*)d_in[5];
  const float* W2s = (const float*)d_in[6];
  const float* W2n = (const float*)d_in[7];
  const float* b2  = (const float*)d_in[8];
  float* out = (float*)d_out;

  // workspace: ushort region then f32 region (46.1 MB total)
  const size_t a1_sz = (size_t)BQ * M1 * 1024;      // 9,437,184 us
  const size_t a2_sz = (size_t)BQ * M2 * 1024;      // 8,388,608 us
  const size_t wf_sz = (size_t)16 * 16 * 2 * 512;   // 262,144 us per layer
  const size_t us_total = a1_sz + a2_sz + 2 * wf_sz;
  const size_t h1_sz = (size_t)BQ * M1 * FEATC;     // 2,359,296 f32
  const size_t need = us_total * sizeof(ushort) + h1_sz * sizeof(float);
  if (ws_size < need) return;

  ushort* p = (ushort*)d_ws;
  ushort* A1F = p; p += a1_sz;
  ushort* A2F = p; p += a2_sz;
  ushort* WF1 = p; p += wf_sz;
  ushort* WF2 = p; p += wf_sz;
  float* h1f32 = (float*)p;

  prep_fused<<<640, 256, 0, stream>>>(x, nodes, W1s, W1n, W2s, W2n,
                                      A1F, WF1, WF2);
  gemm_mfma<<<dim3((BQ * M1) / 64, FEATC / 64), 256, 0, stream>>>(
      A1F, WF1, b1, h1f32);
  prep2_kernel<<<512, 256, 0, stream>>>(h1f32, A2F);
  gemm_mfma<<<dim3((BQ * M2) / 64, FEATC / 64), 256, 0, stream>>>(
      A2F, WF2, b2, out);
}

// Round 11
// 45.475 us; speedup vs baseline: 2.1871x; 1.0504x over previous
//
#include <hip/hip_runtime.h>
#include <hip/hip_bf16.h>

// SparseGCM: 2-layer causal-window GCN on MI355X — split-bf16, fragment-
// contiguous layout, inline-asm depth-4 prefetch MFMA GEMM, burst-write preps,
// XCD writer/reader colocation, fast-tanh epilogue, setprio MFMA clusters.
//
// Edges are j->i for j in [i-16,i) per batch, weights normalize to 1.0 ->
// "gather+segment_sum" == 16-wide sliding-window sum. Only outputs i in
// [512,640) matter: layer1 computes i in [496,640).
//
// Precision (R2/R4): single-bf16 fails (correlated L1 errors x16-amplified by
// the L2 window sum). Split v = hi+lo bf16; compute Ahi*Whi + Ahi*Wlo +
// Alo*Whi (3 MFMAs) ~= fp32. Validated R5-R10 (absmax 0.0039).
//
// Perf history: R5 61.2; R6 99.5 (compiler ate reg pipeline); R7 55.8 (asm
// depth-3 + frag layout); R8 49.7 (depth-4 + burst writes); R9 ABORT (mixing
// compiler vmem with in-flight asm loads corrupts vmcnt bookkeeping); R10
// 47.8 (XCD colocation). R11: (a) epilogue tanhf (libm, ~35 VALU insts x16
// per thread ~= cost of the whole MFMA loop) -> exp2+rcp fast tanh (~6 ops);
// (b) s_setprio(1) around MFMA clusters (independent waves => T5 regime).

namespace {

constexpr int BQ    = 64;
constexpr int FEATC = 256;
constexpr int M1 = 144;   // layer-1 rows/batch: i in [496,640)
constexpr int M2 = 128;   // layer-2 rows/batch: i in [512,640)

using ushort = unsigned short;
using short8 = __attribute__((ext_vector_type(8))) short;   // 8 bf16
using f32x4  = __attribute__((ext_vector_type(4))) float;

__device__ __forceinline__ ushort f2bf(float f) {  // RNE
  union { float f; unsigned u; } v{f};
  unsigned r = v.u + 0x7FFFu + ((v.u >> 16) & 1u);
  return (ushort)(r >> 16);
}
__device__ __forceinline__ float bf2f(ushort h) {
  union { unsigned u; float f; } v{(unsigned)h << 16};
  return v.f;
}
__device__ __forceinline__ void split2(float v, ushort& hi, ushort& lo) {
  hi = f2bf(v);
  lo = f2bf(v - bf2f(hi));
}
// tanh(x) = 1 - 2/(1 + exp2(2*log2e*x)); v_exp_f32/v_rcp_f32 handle the
// limits (exp2 -> 0 / inf gives -1 / +1). |err| ~1e-6 << 2e-2 budget.
__device__ __forceinline__ float tanh_fast(float x) {
  const float e = __builtin_amdgcn_exp2f(x * 2.8853900817779268f);
  return 1.0f - 2.0f * __builtin_amdgcn_rcpf(1.0f + e);
}

// Fragment-contiguous layout. Row r, packed k in [0,512) ([self|win] for A,
// [Wself|Wnbr] for W), s = hi(0)/lo(1) (for W: W1/W2). A wave's MFMA fragment
// = contiguous 1KB block at ((rg*16 + kb)*2 + s)*512, lane-linear inside.
__device__ __forceinline__ size_t frag_idx(int row, int k, int s) {
  return ((size_t)(((row >> 4) * 16 + (k >> 5)) * 2 + s)) * 512
       + ((k >> 3) & 3) * 128 + (row & 15) * 8 + (k & 7);
}
// Same, local to one 16-row group (16384-elem block).
__device__ __forceinline__ int lofs(int row_l, int k, int s) {
  return ((k >> 5) * 2 + s) * 512 + ((k >> 3) & 3) * 128 + row_l * 8 + (k & 7);
}

// ---------------------------------------------------------------------------
// prep_fused: blocks [0,576) = prep1 (A1F via LDS burst, XCD-colocated);
//             blocks [576,640) = weight transpose+split.
// XCD colocation: block p handles memory group G = 4*(p%144) + (p/144), so
// writer XCD p%8 == (G/4)%8 == reader gemm1 panel XCD.
// ---------------------------------------------------------------------------
__global__ __launch_bounds__(256) void prep_fused(
    const float* __restrict__ x, const float* __restrict__ nodes,
    const float* __restrict__ W1s, const float* __restrict__ W1n,
    const float* __restrict__ W2s, const float* __restrict__ W2n,
    ushort* __restrict__ A1F, ushort* __restrict__ WF1,
    ushort* __restrict__ WF2) {
  __shared__ ushort lds_o[16384];   // one 16-row frag group (32 KB)
  __shared__ float tile[64][65];
  const int blk = blockIdx.x;
  if (blk < 576) {
    const int G = 4 * (blk % 144) + (blk / 144);   // XCD-colocation permutation
    const int b = G / 9, c = G % 9, f = threadIdx.x;
    const int t0 = c * 16, i0 = 496 + t0;
    const float* nb = nodes + ((size_t)b * 640) * FEATC + f;
    const float* xb = x     + ((size_t)b * 128) * FEATC + f;

    float v[32];
    #pragma unroll
    for (int d = 0; d < 32; ++d) {
      const int i = i0 - 16 + d;
      v[d] = (i < 512) ? nb[(size_t)i * FEATC] : xb[(size_t)(i - 512) * FEATC];
    }
    float win = 0.f;
    #pragma unroll
    for (int d = 0; d < 16; ++d) win += v[d];

    #pragma unroll
    for (int tt = 0; tt < 16; ++tt) {
      ushort hi, lo;
      split2(v[16 + tt], hi, lo);
      lds_o[lofs(tt, f, 0)] = hi;
      lds_o[lofs(tt, f, 1)] = lo;
      split2(win, hi, lo);
      lds_o[lofs(tt, 256 + f, 0)] = hi;
      lds_o[lofs(tt, 256 + f, 1)] = lo;
      win += v[16 + tt] - v[tt];
    }
    __syncthreads();
    ushort* dst = A1F + (size_t)G * 16384;
    #pragma unroll
    for (int it = 0; it < 8; ++it) {
      const int idx = it * 256 + threadIdx.x;
      *(short8*)(dst + idx * 8) = *(const short8*)(lds_o + idx * 8);
    }
  } else {
    const int w = blk - 576;
    const int z = w >> 4, rem = w & 15;
    const int k0 = (rem >> 2) * 64, n0 = (rem & 3) * 64;
    const float* src = (z == 0) ? W1s : (z == 1) ? W1n : (z == 2) ? W2s : W2n;
    ushort* dst = (z < 2) ? WF1 : WF2;
    const int koff = (z & 1) * 256;
    const int c = threadIdx.x & 63, r4 = threadIdx.x >> 6;
    #pragma unroll
    for (int p = 0; p < 16; ++p) {
      const int k = r4 + p * 4;
      tile[k][c] = src[(size_t)(k0 + k) * FEATC + n0 + c];
    }
    __syncthreads();
    #pragma unroll
    for (int p = 0; p < 16; ++p) {
      const int n = r4 + p * 4;
      ushort hi, lo;
      split2(tile[c][n], hi, lo);
      dst[frag_idx(n0 + n, koff + k0 + c, 0)] = hi;   // W1 (hi) slot
      dst[frag_idx(n0 + n, koff + k0 + c, 1)] = lo;   // W2 (lo) slot
    }
  }
}

// ---------------------------------------------------------------------------
// prep2: build A2F (self + window frag segments) from row-major h1f32.
// 1D grid of 512, XCD-colocated: block p handles group G2 = 4*(p%128)+(p/128)
// (writer XCD p%8 == (G2/4)%8 == reader gemm2 panel XCD). Group G2 covers
// output rows r2 = 16*G2 .. +16 (b = G2/8, t0 = (G2%8)*16).
// ---------------------------------------------------------------------------
__global__ __launch_bounds__(256) void prep2_kernel(
    const float* __restrict__ h1f32, ushort* __restrict__ A2F) {
  __shared__ ushort lds_o[16384];
  const int G2 = 4 * ((int)blockIdx.x % 128) + ((int)blockIdx.x / 128);
  const int b = G2 >> 3, c = G2 & 7, f = threadIdx.x;
  const int t0 = c * 16;
  const float* hp = h1f32 + ((size_t)(b * M1 + t0)) * FEATC + f;

  float hv[32];
  #pragma unroll
  for (int d = 0; d < 32; ++d) hv[d] = hp[(size_t)d * FEATC];
  float win = 0.f;
  #pragma unroll
  for (int d = 0; d < 16; ++d) win += hv[d];

  #pragma unroll
  for (int tt = 0; tt < 16; ++tt) {
    ushort hi, lo;
    split2(hv[16 + tt], hi, lo);          // self = h1 row t+16
    lds_o[lofs(tt, f, 0)] = hi;
    lds_o[lofs(tt, f, 1)] = lo;
    split2(win, hi, lo);                  // window sum [t, t+16)
    lds_o[lofs(tt, 256 + f, 0)] = hi;
    lds_o[lofs(tt, 256 + f, 1)] = lo;
    win += hv[16 + tt] - hv[tt];
  }
  __syncthreads();
  ushort* dst = A2F + (size_t)G2 * 16384;
  #pragma unroll
  for (int it = 0; it < 8; ++it) {
    const int idx = it * 256 + threadIdx.x;
    *(short8*)(dst + idx * 8) = *(const short8*)(lds_o + idx * 8);
  }
}

// ---------------------------------------------------------------------------
// Depth-4 asm-pipelined split-bf16 MFMA GEMM + bias + tanh (no LDS/barriers).
// Block = 4 independent waves (2x2); wave tile 32x32; 16 K-steps of 32.
// 5 rotating buffers, 40 loads in flight, steady s_waitcnt vmcnt(32).
// ONLY asm vmem inside the pipelined region (R9 lesson). Row-major f32 out.
// ---------------------------------------------------------------------------
struct FB { short8 ah0, ah1, al0, al1, b10, b11, b20, b21; };

#define GLOAD(dst, ptr)                                                      \
  asm volatile("global_load_dwordx4 %0, %1, off"                             \
               : "=v"(dst) : "v"(ptr) : "memory")

#define LOADI(Q, tt) do {                                                    \
  GLOAD(Q.ah0, baseA00 + (tt) * 1024);                                       \
  GLOAD(Q.ah1, baseA10 + (tt) * 1024);                                       \
  GLOAD(Q.al0, baseA01 + (tt) * 1024);                                       \
  GLOAD(Q.al1, baseA11 + (tt) * 1024);                                       \
  GLOAD(Q.b10, baseW0h + (tt) * 1024);                                       \
  GLOAD(Q.b11, baseW1h + (tt) * 1024);                                       \
  GLOAD(Q.b20, baseW0l + (tt) * 1024);                                       \
  GLOAD(Q.b21, baseW1l + (tt) * 1024);                                       \
} while (0)

#define WAITV(n) do {                                                        \
  asm volatile("s_waitcnt vmcnt(" #n ")" ::: "memory");                      \
  __builtin_amdgcn_sched_barrier(0);                                         \
} while (0)

#define MF(a, b, c) c = __builtin_amdgcn_mfma_f32_16x16x32_bf16(a, b, c, 0, 0, 0)

#define COMP(Q) do {                                                         \
  __builtin_amdgcn_s_setprio(1);                                             \
  MF(Q.ah0, Q.b10, acc00); MF(Q.ah0, Q.b11, acc01);                          \
  MF(Q.ah1, Q.b10, acc10); MF(Q.ah1, Q.b11, acc11);                          \
  MF(Q.ah0, Q.b20, acc00); MF(Q.ah0, Q.b21, acc01);                          \
  MF(Q.ah1, Q.b20, acc10); MF(Q.ah1, Q.b21, acc11);                          \
  MF(Q.al0, Q.b10, acc00); MF(Q.al0, Q.b11, acc01);                          \
  MF(Q.al1, Q.b10, acc10); MF(Q.al1, Q.b11, acc11);                          \
  __builtin_amdgcn_s_setprio(0);                                             \
  __builtin_amdgcn_sched_barrier(0);                                         \
} while (0)

__global__ __launch_bounds__(256, 2) void gemm_mfma(
    const ushort* __restrict__ A, const ushort* __restrict__ W,
    const float* __restrict__ bias, float* __restrict__ out) {
  const int t = threadIdx.x;
  const int wave = t >> 6, lane = t & 63;
  const int lr = lane & 15, kg = lane >> 4;
  const int m0 = blockIdx.x * 64 + (wave >> 1) * 32;
  const int n0 = blockIdx.y * 64 + (wave & 1) * 32;
  const int rg0 = m0 >> 4, ng0 = n0 >> 4;

  const ushort* baseA00 = A + ((size_t)((rg0 + 0) * 32 + 0)) * 512 + lane * 8;
  const ushort* baseA01 = A + ((size_t)((rg0 + 0) * 32 + 1)) * 512 + lane * 8;
  const ushort* baseA10 = A + ((size_t)((rg0 + 1) * 32 + 0)) * 512 + lane * 8;
  const ushort* baseA11 = A + ((size_t)((rg0 + 1) * 32 + 1)) * 512 + lane * 8;
  const ushort* baseW0h = W + ((size_t)((ng0 + 0) * 32 + 0)) * 512 + lane * 8;
  const ushort* baseW0l = W + ((size_t)((ng0 + 0) * 32 + 1)) * 512 + lane * 8;
  const ushort* baseW1h = W + ((size_t)((ng0 + 1) * 32 + 0)) * 512 + lane * 8;
  const ushort* baseW1l = W + ((size_t)((ng0 + 1) * 32 + 1)) * 512 + lane * 8;

  f32x4 acc00 = {}, acc01 = {}, acc10 = {}, acc11 = {};
  FB q0, q1, q2, q3, q4;

  LOADI(q0, 0); LOADI(q1, 1); LOADI(q2, 2); LOADI(q3, 3); LOADI(q4, 4);
  WAITV(32); COMP(q0); LOADI(q0, 5);
  WAITV(32); COMP(q1); LOADI(q1, 6);
  WAITV(32); COMP(q2); LOADI(q2, 7);
  WAITV(32); COMP(q3); LOADI(q3, 8);
  WAITV(32); COMP(q4); LOADI(q4, 9);
  WAITV(32); COMP(q0); LOADI(q0, 10);
  WAITV(32); COMP(q1); LOADI(q1, 11);
  WAITV(32); COMP(q2); LOADI(q2, 12);
  WAITV(32); COMP(q3); LOADI(q3, 13);
  WAITV(32); COMP(q4); LOADI(q4, 14);
  WAITV(32); COMP(q0); LOADI(q0, 15);
  WAITV(32); COMP(q1);
  WAITV(24); COMP(q2);
  WAITV(16); COMP(q3);
  WAITV(8);  COMP(q4);
  WAITV(0);  COMP(q0);

  // epilogue: bias + fast tanh, row-major f32 out
  const float bv0 = bias[n0 + lr];
  const float bv1 = bias[n0 + 16 + lr];
  auto epi = [&](const f32x4& a, int mt, int nt, float bv) {
    #pragma unroll
    for (int r = 0; r < 4; ++r) {
      const int row = m0 + mt * 16 + kg * 4 + r;
      const int col = n0 + nt * 16 + lr;
      out[(size_t)row * FEATC + col] = tanh_fast(a[r] + bv);
    }
  };
  epi(acc00, 0, 0, bv0);
  epi(acc01, 0, 1, bv1);
  epi(acc10, 1, 0, bv0);
  epi(acc11, 1, 1, bv1);
}

}  // namespace

extern "C" void kernel_launch(void* const* d_in, const int* in_sizes, int n_in,
                              void* d_out, int out_size, void* d_ws, size_t ws_size,
                              hipStream_t stream) {
  const float* x     = (const float*)d_in[0];
  const float* nodes = (const float*)d_in[1];
  // d_in[2] = edge_weight: forward value ew/ew == 1.0 -> unused.
  const float* W1s = (const float*)d_in[3];
  const float* W1n = (const float*)d_in[4];
  const float* b1  = (const float*)d_in[5];
  const float* W2s = (const float*)d_in[6];
  const float* W2n = (const float*)d_in[7];
  const float* b2  = (const float*)d_in[8];
  float* out = (float*)d_out;

  // workspace: ushort region then f32 region (46.1 MB total)
  const size_t a1_sz = (size_t)BQ * M1 * 1024;      // 9,437,184 us
  const size_t a2_sz = (size_t)BQ * M2 * 1024;      // 8,388,608 us
  const size_t wf_sz = (size_t)16 * 16 * 2 * 512;   // 262,144 us per layer
  const size_t us_total = a1_sz + a2_sz + 2 * wf_sz;
  const size_t h1_sz = (size_t)BQ * M1 * FEATC;     // 2,359,296 f32
  const size_t need = us_total * sizeof(ushort) + h1_sz * sizeof(float);
  if (ws_size < need) return;

  ushort* p = (ushort*)d_ws;
  ushort* A1F = p; p += a1_sz;
  ushort* A2F = p; p += a2_sz;
  ushort* WF1 = p; p += wf_sz;
  ushort* WF2 = p; p += wf_sz;
  float* h1f32 = (float*)p;

  prep_fused<<<640, 256, 0, stream>>>(x, nodes, W1s, W1n, W2s, W2n,
                                      A1F, WF1, WF2);
  gemm_mfma<<<dim3((BQ * M1) / 64, FEATC / 64), 256, 0, stream>>>(
      A1F, WF1, b1, h1f32);
  prep2_kernel<<<512, 256, 0, stream>>>(h1f32, A2F);
  gemm_mfma<<<dim3((BQ * M2) / 64, FEATC / 64), 256, 0, stream>>>(
      A2F, WF2, b2, out);
}

// Round 12
// 41.220 us; speedup vs baseline: 2.4128x; 1.1032x over previous
//
#include <hip/hip_runtime.h>
#include <hip/hip_bf16.h>

// SparseGCM: 2-layer causal-window GCN on MI355X — split-bf16, fragment-
// contiguous layout, inline-asm depth-4 prefetch MFMA GEMMs, 3-kernel chain:
//   prep_fused -> gemm1_fused (halo + winsum epilogue -> A2F) -> gemm2.
//
// Edges are j->i for j in [i-16,i) per batch, weights normalize to 1.0 ->
// "gather+segment_sum" == 16-wide sliding-window sum. Only outputs i in
// [512,640) matter: layer1 computes i in [496,640).
//
// Precision (R2/R4): single-bf16 fails (correlated L1 errors x16-amplified by
// the L2 window sum). Split v = hi+lo bf16; compute Ahi*Whi + Ahi*Wlo +
// Alo*Whi (3 MFMAs) ~= fp32. Validated R5-R11 (absmax 0.0039).
//
// Perf history: R5 61.2; R6 99.5 (compiler ate reg pipeline); R7 55.8 (asm
// depth-3 + frag layout); R8 49.7 (depth-4 + burst writes); R9 ABORT (mixing
// compiler vmem with in-flight asm loads); R10 47.8 (XCD colocation); R11
// 45.5 (fast tanh + setprio). R12: gemm1 computes 80-row h1 windows (16-row
// halo, stride-64) and its epilogue does winsum+split+A2F-emit in LDS --
// deletes prep2 + h1f32 (19 MB HBM + one launch); grid 512 (no tail);
// gemm1->gemm2 XCD colocation exact by construction.

namespace {

constexpr int BQ    = 64;
constexpr int FEATC = 256;
constexpr int M1 = 144;   // layer-1 rows/batch: i in [496,640)
constexpr int M2 = 128;   // layer-2 rows/batch: i in [512,640)

using ushort = unsigned short;
using short8 = __attribute__((ext_vector_type(8))) short;   // 8 bf16
using f32x4  = __attribute__((ext_vector_type(4))) float;

__device__ __forceinline__ ushort f2bf(float f) {  // RNE
  union { float f; unsigned u; } v{f};
  unsigned r = v.u + 0x7FFFu + ((v.u >> 16) & 1u);
  return (ushort)(r >> 16);
}
__device__ __forceinline__ float bf2f(ushort h) {
  union { unsigned u; float f; } v{(unsigned)h << 16};
  return v.f;
}
__device__ __forceinline__ void split2(float v, ushort& hi, ushort& lo) {
  hi = f2bf(v);
  lo = f2bf(v - bf2f(hi));
}
// tanh(x) = 1 - 2/(1 + exp2(2*log2e*x)); exp2/rcp handle the limits.
__device__ __forceinline__ float tanh_fast(float x) {
  const float e = __builtin_amdgcn_exp2f(x * 2.8853900817779268f);
  return 1.0f - 2.0f * __builtin_amdgcn_rcpf(1.0f + e);
}

// Fragment-contiguous layout. Row r, packed k in [0,512) ([self|win] for A,
// [Wself|Wnbr] for W), s = hi(0)/lo(1) (for W: W1/W2). A wave's MFMA fragment
// = contiguous 1KB block at ((rg*16 + kb)*2 + s)*512, lane-linear inside.
__device__ __forceinline__ size_t frag_idx(int row, int k, int s) {
  return ((size_t)(((row >> 4) * 16 + (k >> 5)) * 2 + s)) * 512
       + ((k >> 3) & 3) * 128 + (row & 15) * 8 + (k & 7);
}
// Same, local to one 16-row group (16384-elem block).
__device__ __forceinline__ int lofs(int row_l, int k, int s) {
  return ((k >> 5) * 2 + s) * 512 + ((k >> 3) & 3) * 128 + row_l * 8 + (k & 7);
}

// ---------------------------------------------------------------------------
// prep_fused: blocks [0,576) = prep1 (A1F via LDS burst, XCD-permuted);
//             blocks [576,640) = weight transpose+split.
// ---------------------------------------------------------------------------
__global__ __launch_bounds__(256) void prep_fused(
    const float* __restrict__ x, const float* __restrict__ nodes,
    const float* __restrict__ W1s, const float* __restrict__ W1n,
    const float* __restrict__ W2s, const float* __restrict__ W2n,
    ushort* __restrict__ A1F, ushort* __restrict__ WF1,
    ushort* __restrict__ WF2) {
  __shared__ ushort lds_o[16384];   // one 16-row frag group (32 KB)
  __shared__ float tile[64][65];
  const int blk = blockIdx.x;
  if (blk < 576) {
    const int G = 4 * (blk % 144) + (blk / 144);   // XCD spread permutation
    const int b = G / 9, c = G % 9, f = threadIdx.x;
    const int t0 = c * 16, i0 = 496 + t0;
    const float* nb = nodes + ((size_t)b * 640) * FEATC + f;
    const float* xb = x     + ((size_t)b * 128) * FEATC + f;

    float v[32];
    #pragma unroll
    for (int d = 0; d < 32; ++d) {
      const int i = i0 - 16 + d;
      v[d] = (i < 512) ? nb[(size_t)i * FEATC] : xb[(size_t)(i - 512) * FEATC];
    }
    float win = 0.f;
    #pragma unroll
    for (int d = 0; d < 16; ++d) win += v[d];

    #pragma unroll
    for (int tt = 0; tt < 16; ++tt) {
      ushort hi, lo;
      split2(v[16 + tt], hi, lo);
      lds_o[lofs(tt, f, 0)] = hi;
      lds_o[lofs(tt, f, 1)] = lo;
      split2(win, hi, lo);
      lds_o[lofs(tt, 256 + f, 0)] = hi;
      lds_o[lofs(tt, 256 + f, 1)] = lo;
      win += v[16 + tt] - v[tt];
    }
    __syncthreads();
    ushort* dst = A1F + (size_t)G * 16384;
    #pragma unroll
    for (int it = 0; it < 8; ++it) {
      const int idx = it * 256 + threadIdx.x;
      *(short8*)(dst + idx * 8) = *(const short8*)(lds_o + idx * 8);
    }
  } else {
    const int w = blk - 576;
    const int z = w >> 4, rem = w & 15;
    const int k0 = (rem >> 2) * 64, n0 = (rem & 3) * 64;
    const float* src = (z == 0) ? W1s : (z == 1) ? W1n : (z == 2) ? W2s : W2n;
    ushort* dst = (z < 2) ? WF1 : WF2;
    const int koff = (z & 1) * 256;
    const int c = threadIdx.x & 63, r4 = threadIdx.x >> 6;
    #pragma unroll
    for (int p = 0; p < 16; ++p) {
      const int k = r4 + p * 4;
      tile[k][c] = src[(size_t)(k0 + k) * FEATC + n0 + c];
    }
    __syncthreads();
    #pragma unroll
    for (int p = 0; p < 16; ++p) {
      const int n = r4 + p * 4;
      ushort hi, lo;
      split2(tile[c][n], hi, lo);
      dst[frag_idx(n0 + n, koff + k0 + c, 0)] = hi;   // W1 (hi) slot
      dst[frag_idx(n0 + n, koff + k0 + c, 1)] = lo;   // W2 (lo) slot
    }
  }
}

// ---------------------------------------------------------------------------
// Shared asm helpers (R9 lesson: ONLY asm vmem between first GLOAD and the
// final WAITV(0); all compiler vmem strictly after).
// ---------------------------------------------------------------------------
#define GLOAD(dst, ptr)                                                      \
  asm volatile("global_load_dwordx4 %0, %1, off"                             \
               : "=v"(dst) : "v"(ptr) : "memory")

#define WAITV(n) do {                                                        \
  asm volatile("s_waitcnt vmcnt(" #n ")" ::: "memory");                      \
  __builtin_amdgcn_sched_barrier(0);                                         \
} while (0)

#define MF(a, b, c) c = __builtin_amdgcn_mfma_f32_16x16x32_bf16(a, b, c, 0, 0, 0)

// ---------------------------------------------------------------------------
// gemm1_fused: layer-1 GEMM over an 80-row h1 window (16-row halo), winsum
// epilogue emits A2F fragment groups directly. Grid (128, 4): mx2 = 2b+half,
// ny. Wave = one 16-col strip x 80 rows. 16 K-steps of 32; 12 asm loads/step
// (5 A-frag hi/lo pairs + W pair); 4 rotating slots, steady vmcnt(36).
// ---------------------------------------------------------------------------
struct FJ { short8 a0h, a0l, a1h, a1l, a2h, a2l, a3h, a3l, a4h, a4l, wh, wl; };

#define LOADJ(Q, kb) do {                                                    \
  GLOAD(Q.a0h, bA0 + (kb) * 1024); GLOAD(Q.a0l, bA0 + (kb) * 1024 + 512);    \
  GLOAD(Q.a1h, bA1 + (kb) * 1024); GLOAD(Q.a1l, bA1 + (kb) * 1024 + 512);    \
  GLOAD(Q.a2h, bA2 + (kb) * 1024); GLOAD(Q.a2l, bA2 + (kb) * 1024 + 512);    \
  GLOAD(Q.a3h, bA3 + (kb) * 1024); GLOAD(Q.a3l, bA3 + (kb) * 1024 + 512);    \
  GLOAD(Q.a4h, bA4 + (kb) * 1024); GLOAD(Q.a4l, bA4 + (kb) * 1024 + 512);    \
  GLOAD(Q.wh,  bW  + (kb) * 1024); GLOAD(Q.wl,  bW  + (kb) * 1024 + 512);    \
} while (0)

#define COMPJ(Q) do {                                                        \
  __builtin_amdgcn_s_setprio(1);                                             \
  MF(Q.a0h, Q.wh, acc[0]); MF(Q.a1h, Q.wh, acc[1]); MF(Q.a2h, Q.wh, acc[2]); \
  MF(Q.a3h, Q.wh, acc[3]); MF(Q.a4h, Q.wh, acc[4]);                          \
  MF(Q.a0h, Q.wl, acc[0]); MF(Q.a1h, Q.wl, acc[1]); MF(Q.a2h, Q.wl, acc[2]); \
  MF(Q.a3h, Q.wl, acc[3]); MF(Q.a4h, Q.wl, acc[4]);                          \
  MF(Q.a0l, Q.wh, acc[0]); MF(Q.a1l, Q.wh, acc[1]); MF(Q.a2l, Q.wh, acc[2]); \
  MF(Q.a3l, Q.wh, acc[3]); MF(Q.a4l, Q.wh, acc[4]);                          \
  __builtin_amdgcn_s_setprio(0);                                             \
  __builtin_amdgcn_sched_barrier(0);                                         \
} while (0)

__global__ __launch_bounds__(256, 2) void gemm1_fused(
    const ushort* __restrict__ A, const ushort* __restrict__ W,
    const float* __restrict__ bias, ushort* __restrict__ A2F) {
  __shared__ float hvt[80][68];     // padded: stride 68 -> 2-way max on write
  __shared__ ushort outb[16384];    // A2F staging: 32 units x 512

  const int tid = threadIdx.x;
  const int wave = tid >> 6, lane = tid & 63;
  const int lr = lane & 15, kg = lane >> 4;
  const int mx2 = blockIdx.x, ny = blockIdx.y;
  const int b = mx2 >> 1, half = mx2 & 1;
  const int rgA0 = 9 * b + 4 * half;          // first of 5 A row-groups
  const int n0 = ny * 64;
  const int ngw = ny * 4 + wave;              // W col-group for this wave

  const ushort* bA0 = A + (size_t)(rgA0 + 0) * 16384 + lane * 8;
  const ushort* bA1 = A + (size_t)(rgA0 + 1) * 16384 + lane * 8;
  const ushort* bA2 = A + (size_t)(rgA0 + 2) * 16384 + lane * 8;
  const ushort* bA3 = A + (size_t)(rgA0 + 3) * 16384 + lane * 8;
  const ushort* bA4 = A + (size_t)(rgA0 + 4) * 16384 + lane * 8;
  const ushort* bW  = W + (size_t)ngw * 16384 + lane * 8;

  f32x4 acc[5] = {};
  FJ q0, q1, q2, q3;

  LOADJ(q0, 0); LOADJ(q1, 1); LOADJ(q2, 2); LOADJ(q3, 3);
  WAITV(36); COMPJ(q0); LOADJ(q0, 4);
  WAITV(36); COMPJ(q1); LOADJ(q1, 5);
  WAITV(36); COMPJ(q2); LOADJ(q2, 6);
  WAITV(36); COMPJ(q3); LOADJ(q3, 7);
  WAITV(36); COMPJ(q0); LOADJ(q0, 8);
  WAITV(36); COMPJ(q1); LOADJ(q1, 9);
  WAITV(36); COMPJ(q2); LOADJ(q2, 10);
  WAITV(36); COMPJ(q3); LOADJ(q3, 11);
  WAITV(36); COMPJ(q0); LOADJ(q0, 12);
  WAITV(36); COMPJ(q1); LOADJ(q1, 13);
  WAITV(36); COMPJ(q2); LOADJ(q2, 14);
  WAITV(36); COMPJ(q3); LOADJ(q3, 15);
  WAITV(36); COMPJ(q0);
  WAITV(24); COMPJ(q1);
  WAITV(12); COMPJ(q2);
  WAITV(0);  COMPJ(q3);

  // ---- epilogue 1: tanh -> LDS f32 tile [80 rows][64 cols] ----
  const float bv = bias[n0 + wave * 16 + lr];
  #pragma unroll
  for (int fr = 0; fr < 5; ++fr)
    #pragma unroll
    for (int r = 0; r < 4; ++r)
      hvt[fr * 16 + kg * 4 + r][wave * 16 + lr] = tanh_fast(acc[fr][r] + bv);
  __syncthreads();

  // ---- epilogue 2: per-column 16-window sums + split -> outb units ----
  // thread = (q = tid>>6, col = tid&63); A2 rows t = q*16 + tt, tt in [0,16).
  // self = hv[t+16], win = sum hv[t..t+16). Same numerics as old prep2.
  {
    const int col = tid & 63, q = tid >> 6;
    float hv[32];
    #pragma unroll
    for (int d = 0; d < 32; ++d) hv[d] = hvt[q * 16 + d][col];
    float win = 0.f;
    #pragma unroll
    for (int d = 0; d < 16; ++d) win += hv[d];

    const int su = ((q * 4 + (col >> 5)) * 2) * 512
                 + ((col >> 3) & 3) * 128 + (col & 7);
    const int wu = ((q * 4 + 2 + (col >> 5)) * 2) * 512
                 + ((col >> 3) & 3) * 128 + (col & 7);
    #pragma unroll
    for (int tt = 0; tt < 16; ++tt) {
      ushort hi, lo;
      split2(hv[16 + tt], hi, lo);
      outb[su + tt * 8]       = hi;
      outb[su + tt * 8 + 512] = lo;
      split2(win, hi, lo);
      outb[wu + tt * 8]       = hi;
      outb[wu + tt * 8 + 512] = lo;
      win += hv[16 + tt] - hv[tt];
    }
  }
  __syncthreads();

  // ---- epilogue 3: burst copy 32 units of 1KB to A2F ----
  // local unit u = ((q*4 + kbl)*2 + s); global unit = ((4*mx2+q)*16 + KB)*2+s,
  // KB = kbl<2 ? 2*ny+kbl : 8 + 2*ny + (kbl-2).
  const int rg20 = 4 * mx2;
  #pragma unroll
  for (int it = 0; it < 8; ++it) {
    const int lin = it * 2048 + tid * 8;
    const int u = lin >> 9, w = lin & 511;
    const int uq = u >> 3, ukbl = (u >> 1) & 3, us = u & 1;
    const int KB = (ukbl < 2) ? (2 * ny + ukbl) : (8 + 2 * ny + (ukbl - 2));
    const size_t dst = ((size_t)((rg20 + uq) * 16 + KB) * 2 + us) * 512 + w;
    *(short8*)(A2F + dst) = *(const short8*)(outb + lin);
  }
}

// ---------------------------------------------------------------------------
// gemm2 (unchanged R11): depth-4 asm pipeline, wave tile 32x32, fast tanh,
// row-major f32 out.
// ---------------------------------------------------------------------------
struct FB { short8 ah0, ah1, al0, al1, b10, b11, b20, b21; };

#define LOADI(Q, tt) do {                                                    \
  GLOAD(Q.ah0, baseA00 + (tt) * 1024);                                       \
  GLOAD(Q.ah1, baseA10 + (tt) * 1024);                                       \
  GLOAD(Q.al0, baseA01 + (tt) * 1024);                                       \
  GLOAD(Q.al1, baseA11 + (tt) * 1024);                                       \
  GLOAD(Q.b10, baseW0h + (tt) * 1024);                                       \
  GLOAD(Q.b11, baseW1h + (tt) * 1024);                                       \
  GLOAD(Q.b20, baseW0l + (tt) * 1024);                                       \
  GLOAD(Q.b21, baseW1l + (tt) * 1024);                                       \
} while (0)

#define COMP(Q) do {                                                         \
  __builtin_amdgcn_s_setprio(1);                                             \
  MF(Q.ah0, Q.b10, acc00); MF(Q.ah0, Q.b11, acc01);                          \
  MF(Q.ah1, Q.b10, acc10); MF(Q.ah1, Q.b11, acc11);                          \
  MF(Q.ah0, Q.b20, acc00); MF(Q.ah0, Q.b21, acc01);                          \
  MF(Q.ah1, Q.b20, acc10); MF(Q.ah1, Q.b21, acc11);                          \
  MF(Q.al0, Q.b10, acc00); MF(Q.al0, Q.b11, acc01);                          \
  MF(Q.al1, Q.b10, acc10); MF(Q.al1, Q.b11, acc11);                          \
  __builtin_amdgcn_s_setprio(0);                                             \
  __builtin_amdgcn_sched_barrier(0);                                         \
} while (0)

__global__ __launch_bounds__(256, 2) void gemm_mfma(
    const ushort* __restrict__ A, const ushort* __restrict__ W,
    const float* __restrict__ bias, float* __restrict__ out) {
  const int t = threadIdx.x;
  const int wave = t >> 6, lane = t & 63;
  const int lr = lane & 15, kg = lane >> 4;
  const int m0 = blockIdx.x * 64 + (wave >> 1) * 32;
  const int n0 = blockIdx.y * 64 + (wave & 1) * 32;
  const int rg0 = m0 >> 4, ng0 = n0 >> 4;

  const ushort* baseA00 = A + ((size_t)((rg0 + 0) * 32 + 0)) * 512 + lane * 8;
  const ushort* baseA01 = A + ((size_t)((rg0 + 0) * 32 + 1)) * 512 + lane * 8;
  const ushort* baseA10 = A + ((size_t)((rg0 + 1) * 32 + 0)) * 512 + lane * 8;
  const ushort* baseA11 = A + ((size_t)((rg0 + 1) * 32 + 1)) * 512 + lane * 8;
  const ushort* baseW0h = W + ((size_t)((ng0 + 0) * 32 + 0)) * 512 + lane * 8;
  const ushort* baseW0l = W + ((size_t)((ng0 + 0) * 32 + 1)) * 512 + lane * 8;
  const ushort* baseW1h = W + ((size_t)((ng0 + 1) * 32 + 0)) * 512 + lane * 8;
  const ushort* baseW1l = W + ((size_t)((ng0 + 1) * 32 + 1)) * 512 + lane * 8;

  f32x4 acc00 = {}, acc01 = {}, acc10 = {}, acc11 = {};
  FB q0, q1, q2, q3, q4;

  LOADI(q0, 0); LOADI(q1, 1); LOADI(q2, 2); LOADI(q3, 3); LOADI(q4, 4);
  WAITV(32); COMP(q0); LOADI(q0, 5);
  WAITV(32); COMP(q1); LOADI(q1, 6);
  WAITV(32); COMP(q2); LOADI(q2, 7);
  WAITV(32); COMP(q3); LOADI(q3, 8);
  WAITV(32); COMP(q4); LOADI(q4, 9);
  WAITV(32); COMP(q0); LOADI(q0, 10);
  WAITV(32); COMP(q1); LOADI(q1, 11);
  WAITV(32); COMP(q2); LOADI(q2, 12);
  WAITV(32); COMP(q3); LOADI(q3, 13);
  WAITV(32); COMP(q4); LOADI(q4, 14);
  WAITV(32); COMP(q0); LOADI(q0, 15);
  WAITV(32); COMP(q1);
  WAITV(24); COMP(q2);
  WAITV(16); COMP(q3);
  WAITV(8);  COMP(q4);
  WAITV(0);  COMP(q0);

  const float bv0 = bias[n0 + lr];
  const float bv1 = bias[n0 + 16 + lr];
  auto epi = [&](const f32x4& a, int mt, int nt, float bv) {
    #pragma unroll
    for (int r = 0; r < 4; ++r) {
      const int row = m0 + mt * 16 + kg * 4 + r;
      const int col = n0 + nt * 16 + lr;
      out[(size_t)row * FEATC + col] = tanh_fast(a[r] + bv);
    }
  };
  epi(acc00, 0, 0, bv0);
  epi(acc01, 0, 1, bv1);
  epi(acc10, 1, 0, bv0);
  epi(acc11, 1, 1, bv1);
}

}  // namespace

extern "C" void kernel_launch(void* const* d_in, const int* in_sizes, int n_in,
                              void* d_out, int out_size, void* d_ws, size_t ws_size,
                              hipStream_t stream) {
  const float* x     = (const float*)d_in[0];
  const float* nodes = (const float*)d_in[1];
  // d_in[2] = edge_weight: forward value ew/ew == 1.0 -> unused.
  const float* W1s = (const float*)d_in[3];
  const float* W1n = (const float*)d_in[4];
  const float* b1  = (const float*)d_in[5];
  const float* W2s = (const float*)d_in[6];
  const float* W2n = (const float*)d_in[7];
  const float* b2  = (const float*)d_in[8];
  float* out = (float*)d_out;

  // workspace (ushort): A1F + A2F + WF1 + WF2 = 36.7 MB (< R11's 46.1, fits)
  const size_t a1_sz = (size_t)BQ * M1 * 1024;      // 9,437,184
  const size_t a2_sz = (size_t)BQ * M2 * 1024;      // 8,388,608
  const size_t wf_sz = (size_t)16 * 16 * 2 * 512;   // 262,144 per layer
  const size_t need = (a1_sz + a2_sz + 2 * wf_sz) * sizeof(ushort);
  if (ws_size < need) return;

  ushort* p = (ushort*)d_ws;
  ushort* A1F = p; p += a1_sz;
  ushort* A2F = p; p += a2_sz;
  ushort* WF1 = p; p += wf_sz;
  ushort* WF2 = p; p += wf_sz;

  prep_fused<<<640, 256, 0, stream>>>(x, nodes, W1s, W1n, W2s, W2n,
                                      A1F, WF1, WF2);
  gemm1_fused<<<dim3(BQ * 2, FEATC / 64), 256, 0, stream>>>(A1F, WF1, b1, A2F);
  gemm_mfma<<<dim3((BQ * M2) / 64, FEATC / 64), 256, 0, stream>>>(
      A2F, WF2, b2, out);
}